// Round 1
// baseline (1417.785 us; speedup 1.0000x reference)
//
#include <hip/hip_runtime.h>
#include <hip/hip_bf16.h>
#include <math.h>

// MotionNet: PointNet++-style 2-level SA.  B=32, L=16, N=512.
// M = B*npoint*nsample = 131072 for all four conv layers.
//
// Pipeline per SA module:
//   shift -> FPS (serial, wave/batch) -> gather q -> ball query (builds X, gate)
//   -> conv_a -> stats_a -> conv_b (affine+lrelu of a folded in) -> stats_b
//   -> pool (affine+lrelu+gate+max folded in)
//
// Exactness discipline: FPS argmax + ballquery mask use __fmul_rn/__fadd_rn
// (no FMA contraction) to bit-match the reference op order; index selection
// replicates jnp.argmax first-max and sort-ascending-index semantics.
// Everything value-like is bf16-tolerant (threshold ~2% of absmax), so big
// intermediates are stored bf16, computed f32.

#define BATCH 32
#define MCOLS 131072

typedef __hip_bfloat16 bf16;

// ---------------------------------------------------------------- shift
template<int N>
__global__ void shift_kernel(const float* __restrict__ xyz, float* __restrict__ qout) {
    int t = blockIdx.x * 256 + threadIdx.x;
    if (t >= BATCH * N * 3) return;
    int c = t % 3;
    int n = (t / 3) % N;
    int b = t / (3 * N);
    int l = b & 15;
    float v;
    if (l < 15) {
        v = xyz[((size_t)(b + 1) * N + n) * 3 + c];
    } else {
        int g0 = b - 15;
        float acc = 0.f;
        for (int i = 0; i < 15; ++i) {
            float d = __fsub_rn(xyz[((size_t)(g0 + i + 1) * N + n) * 3 + c],
                                xyz[((size_t)(g0 + i) * N + n) * 3 + c]);
            acc = __fadd_rn(acc, d);
        }
        v = __fadd_rn(xyz[((size_t)b * N + n) * 3 + c], __fdiv_rn(acc, 15.f));
    }
    qout[t] = v;   // t == (b*N+n)*3+c
}

// ---------------------------------------------------------------- FPS
// One wave (64 threads) per batch.  q points cached in LDS, mind[] in regs.
// Replicates: idx[0]=0; scan: mind=min(mind,d(last)); last=argmax(mind) (first max).
template<int N, int NPOINT>
__global__ __launch_bounds__(64) void fps_kernel(const float* __restrict__ q,
                                                 int* __restrict__ out) {
    int b = blockIdx.x;
    int lane = threadIdx.x;
    __shared__ float qx[N], qy[N], qz[N];
    const float* qb = q + (size_t)b * N * 3;
    for (int j = lane; j < N; j += 64) {
        qx[j] = qb[j * 3 + 0];
        qy[j] = qb[j * 3 + 1];
        qz[j] = qb[j * 3 + 2];
    }
    __syncthreads();
    constexpr int P = N / 64;
    float mind[P];
#pragma unroll
    for (int p = 0; p < P; ++p) mind[p] = 1e10f;
    if (lane == 0) out[b * NPOINT] = 0;
    int last = 0;
    for (int s = 1; s < NPOINT; ++s) {
        float lx = qx[last], ly = qy[last], lz = qz[last];
        float best = -1.f;
        int bj = 0x7fffffff;
#pragma unroll
        for (int p = 0; p < P; ++p) {
            int j = p * 64 + lane;                      // ascending j within lane
            float dx = __fsub_rn(qx[j], lx);
            float dy = __fsub_rn(qy[j], ly);
            float dz = __fsub_rn(qz[j], lz);
            float d = __fadd_rn(__fadd_rn(__fmul_rn(dx, dx), __fmul_rn(dy, dy)),
                                __fmul_rn(dz, dz));
            float mn = fminf(mind[p], d);
            mind[p] = mn;
            if (mn > best) { best = mn; bj = j; }       // strict > keeps smallest j
        }
#pragma unroll
        for (int off = 32; off >= 1; off >>= 1) {
            float ob = __shfl_xor(best, off, 64);
            int   oj = __shfl_xor(bj,   off, 64);
            if (ob > best || (ob == best && oj < bj)) { best = ob; bj = oj; }
        }
        last = bj;                                      // uniform across lanes
        if (lane == 0) out[b * NPOINT + s] = last;
    }
}

// ---------------------------------------------------------------- gather q
template<int N, int NPOINT>
__global__ void gather_kernel(const float* __restrict__ src, const int* __restrict__ idx,
                              float* __restrict__ dst) {
    int t = blockIdx.x * 256 + threadIdx.x;
    if (t >= BATCH * NPOINT * 3) return;
    int c = t % 3;
    int i = (t / 3) % NPOINT;
    int b = t / (3 * NPOINT);
    dst[t] = src[((size_t)b * N + idx[b * NPOINT + i]) * 3 + c];
}

// ---------------------------------------------------------------- ball query
// One wave per query point.  Scan N candidates in 64-lane chunks; ballot +
// prefix popcount assigns slots in ascending index order (== sort semantics).
// Pads with first neighbor (or 0 if none).  Builds X ((3+CF) x M, bf16) and
// gate (sigmoid(|dp|), f32).
template<int N, int NPOINT, int NS, int CF, bool PM>
__global__ __launch_bounds__(256) void ballq_kernel(
        const float* __restrict__ xyz,    // (B,N,3)
        const float* __restrict__ qpts,   // (B,NPOINT,3)
        const float* __restrict__ feats,  // PM: (B,N,3)  else (B,CF,N)
        float r2, float radius,
        bf16* __restrict__ X, float* __restrict__ gate) {
    static_assert((NS & (NS - 1)) == 0, "NS pow2");
    int lane = threadIdx.x & 63;
    int wib = threadIdx.x >> 6;
    int wid = blockIdx.x * 4 + wib;
    int b = wid / NPOINT;
    int i = wid % NPOINT;
    const float* qp = qpts + ((size_t)b * NPOINT + i) * 3;
    float qx = qp[0], qy = qp[1], qz = qp[2];
    __shared__ int gsh[4][NS];
    int* gidx = gsh[wib];
    int taken = 0, first = 0;
    bool any = false;
#pragma unroll
    for (int base = 0; base < N; base += 64) {
        int j = base + lane;
        const float* p = xyz + ((size_t)b * N + j) * 3;
        float dx = __fsub_rn(qx, p[0]);
        float dy = __fsub_rn(qy, p[1]);
        float dz = __fsub_rn(qz, p[2]);
        float d2 = __fadd_rn(__fadd_rn(__fmul_rn(dx, dx), __fmul_rn(dy, dy)),
                             __fmul_rn(dz, dz));
        bool in = d2 < r2;
        unsigned long long mk = __ballot(in);
        if (!any && mk) { first = base + __builtin_ctzll(mk); any = true; }
        int cb = __builtin_popcountll(mk & ((1ull << lane) - 1ull));
        int slot = taken + cb;
        if (in && slot < NS) gidx[slot] = j;
        taken += (int)__builtin_popcountll(mk);
    }
    if (taken < NS) {
        for (int s = taken + lane; s < NS; s += 64) gidx[s] = any ? first : 0;
    }
    __syncthreads();   // uniform: fixed trip counts for every wave in block
    int m0 = (b * NPOINT + i) * NS;
    if (lane < NS) {
        int g = gidx[lane];
        const float* p = xyz + ((size_t)b * N + g) * 3;
        float dx = (p[0] - qx) / radius;
        float dy = (p[1] - qy) / radius;
        float dz = (p[2] - qz) / radius;
        float dist = sqrtf(dx * dx + dy * dy + dz * dz);
        gate[m0 + lane] = 1.f / (1.f + expf(-dist));
    }
    constexpr int TOT = NS * (3 + CF);
    for (int e = lane; e < TOT; e += 64) {
        int s = e & (NS - 1);
        int c = e / NS;
        int g = gidx[s];
        float v;
        if (c < 3) {
            float qc = (c == 0) ? qx : ((c == 1) ? qy : qz);
            v = (xyz[((size_t)b * N + g) * 3 + c] - qc) / radius;
        } else {
            v = PM ? feats[((size_t)b * N + g) * 3 + (c - 3)]
                   : feats[((size_t)b * CF + (c - 3)) * N + g];
        }
        X[(size_t)c * MCOLS + m0 + s] = __float2bfloat16(v);
    }
}

// ---------------------------------------------------------------- conv (1x1)
// Thread-per-column: full C-column in registers, read exactly once from HBM.
// W indices are wave-uniform -> scalar loads.  o unrolled x4 for ILP.
// AFF: fold BN affine + leaky-relu of the upstream layer into the load.
template<int C, int O, bool AFF>
__global__ __launch_bounds__(256) void conv_kernel(
        const bf16* __restrict__ X, const float* __restrict__ W,
        const float* __restrict__ ss,   // [scale(C), shift(C)] when AFF
        bf16* __restrict__ Y) {
    int m = blockIdx.x * 256 + threadIdx.x;
    float xcol[C];
#pragma unroll
    for (int c = 0; c < C; ++c) {
        float v = __bfloat162float(X[(size_t)c * MCOLS + m]);
        if constexpr (AFF) {
            v = fmaf(v, ss[c], ss[C + c]);
            v = v > 0.f ? v : 0.2f * v;
        }
        xcol[c] = v;
    }
    for (int o = 0; o < O; o += 4) {
        float a0 = 0.f, a1 = 0.f, a2 = 0.f, a3 = 0.f;
#pragma unroll
        for (int c = 0; c < C; ++c) {
            float x = xcol[c];
            a0 = fmaf(W[(o + 0) * C + c], x, a0);
            a1 = fmaf(W[(o + 1) * C + c], x, a1);
            a2 = fmaf(W[(o + 2) * C + c], x, a2);
            a3 = fmaf(W[(o + 3) * C + c], x, a3);
        }
        Y[(size_t)(o + 0) * MCOLS + m] = __float2bfloat16(a0);
        Y[(size_t)(o + 1) * MCOLS + m] = __float2bfloat16(a1);
        Y[(size_t)(o + 2) * MCOLS + m] = __float2bfloat16(a2);
        Y[(size_t)(o + 3) * MCOLS + m] = __float2bfloat16(a3);
    }
}

// ---------------------------------------------------------------- BN stats
// One block per output channel: sum/sumsq over M, then scale/shift directly.
// No atomics, no zero-init (ws is poison-filled).
__global__ __launch_bounds__(256) void stats_kernel(
        const bf16* __restrict__ Y, int O,
        const float* __restrict__ gm, const float* __restrict__ bt,
        float* __restrict__ norm) {   // [scale(O), shift(O)]
    int o = blockIdx.x;
    const bf16* row = Y + (size_t)o * MCOLS;
    float s = 0.f, s2 = 0.f;
    for (int m = threadIdx.x; m < MCOLS; m += 256) {
        float v = __bfloat162float(row[m]);
        s += v;
        s2 = fmaf(v, v, s2);
    }
#pragma unroll
    for (int off = 32; off >= 1; off >>= 1) {
        s  += __shfl_xor(s,  off, 64);
        s2 += __shfl_xor(s2, off, 64);
    }
    __shared__ float sh[8];
    int wid = threadIdx.x >> 6;
    if ((threadIdx.x & 63) == 0) { sh[wid] = s; sh[4 + wid] = s2; }
    __syncthreads();
    if (threadIdx.x == 0) {
        float S  = sh[0] + sh[1] + sh[2] + sh[3];
        float S2 = sh[4] + sh[5] + sh[6] + sh[7];
        const float invM = 1.f / (float)MCOLS;
        float mu = S * invM;
        float var = S2 * invM - mu * mu;
        float sc = gm[o] * rsqrtf(var + 1e-5f);
        norm[o] = sc;
        norm[O + o] = bt[o] - mu * sc;
    }
}

// ---------------------------------------------------------------- pool
// out[(b*O+o)*NPOINT+n] = max_k gate * lrelu(affine(y))
template<int NS, int NPOINT, int O>
__global__ __launch_bounds__(256) void pool_kernel(
        const bf16* __restrict__ Y, const float* __restrict__ norm,
        const float* __restrict__ gate, float* __restrict__ out) {
    int t = blockIdx.x * 256 + threadIdx.x;   // B*O*NPOINT == 1048576
    int n = t % NPOINT;
    int o = (t / NPOINT) % O;
    int b = t / (NPOINT * O);
    int m0 = (b * NPOINT + n) * NS;
    float sc = norm[o], sf = norm[O + o];
    float best = -INFINITY;
#pragma unroll
    for (int k = 0; k < NS; ++k) {
        float v = fmaf(__bfloat162float(Y[(size_t)o * MCOLS + m0 + k]), sc, sf);
        v = v > 0.f ? v : 0.2f * v;
        best = fmaxf(best, gate[m0 + k] * v);
    }
    out[t] = best;
}

// ---------------------------------------------------------------- launch
extern "C" void kernel_launch(void* const* d_in, const int* in_sizes, int n_in,
                              void* d_out, int out_size, void* d_ws, size_t ws_size,
                              hipStream_t stream) {
    const float* xyz = (const float*)d_in[0];
    const float* w1a = (const float*)d_in[1];
    const float* g1a = (const float*)d_in[2];
    const float* b1a = (const float*)d_in[3];
    const float* w1b = (const float*)d_in[4];
    const float* g1b = (const float*)d_in[5];
    const float* b1b = (const float*)d_in[6];
    const float* w2a = (const float*)d_in[7];
    const float* g2a = (const float*)d_in[8];
    const float* b2a = (const float*)d_in[9];
    const float* w2b = (const float*)d_in[10];
    const float* g2b = (const float*)d_in[11];
    const float* b2b = (const float*)d_in[12];

    char* ws = (char*)d_ws;
    // f32 / int small buffers
    constexpr size_t OFF_QS1   = 0;          // 32*512*3 f      196608 B
    constexpr size_t OFF_IDX1  = 196608;     // 32*256 i         32768 B
    constexpr size_t OFF_Q1C   = 229376;     // 32*256*3 f       98304 B
    constexpr size_t OFF_GATE1 = 327680;     // 131072 f        524288 B
    constexpr size_t OFF_F1    = 851968;     // 32*128*256 f   4194304 B
    constexpr size_t OFF_QS2   = 5046272;    // 32*256*3 f       98304 B
    constexpr size_t OFF_IDX2  = 5144576;    // 32*128 i         16384 B
    constexpr size_t OFF_Q2C   = 5160960;    // 32*128*3 f       49152 B
    constexpr size_t OFF_GATE2 = 5210112;    // 131072 f        524288 B
    constexpr size_t OFF_N1A   = 5734400;    // 2*64 f             512 B
    constexpr size_t OFF_N1B   = 5734912;    // 2*128 f           1024 B
    constexpr size_t OFF_N2A   = 5735936;    // 2*128 f           1024 B
    constexpr size_t OFF_N2B   = 5736960;    // 2*256 f           2048 B
    // bf16 arena (lifetime-overlapped):
    //  BufP: x1 -> y1b -> x2 -> y2b   (max 256*131072 bf16 = 64 MiB)
    //  BufQ: y1a -> y2a               (max 128*131072 bf16 = 32 MiB)
    constexpr size_t OFF_BUFP  = 5739008;    // 67108864 B
    constexpr size_t OFF_BUFQ  = 72847872;   // 33554432 B
    // total: 106402304 B (~101.5 MiB)

    float* qs1   = (float*)(ws + OFF_QS1);
    int*   idx1  = (int*)  (ws + OFF_IDX1);
    float* q1c   = (float*)(ws + OFF_Q1C);
    float* gate1 = (float*)(ws + OFF_GATE1);
    float* f1    = (float*)(ws + OFF_F1);
    float* qs2   = (float*)(ws + OFF_QS2);
    int*   idx2  = (int*)  (ws + OFF_IDX2);
    float* q2c   = (float*)(ws + OFF_Q2C);
    float* gate2 = (float*)(ws + OFF_GATE2);
    float* n1a   = (float*)(ws + OFF_N1A);
    float* n1b   = (float*)(ws + OFF_N1B);
    float* n2a   = (float*)(ws + OFF_N2A);
    float* n2b   = (float*)(ws + OFF_N2B);
    bf16*  bufP  = (bf16*) (ws + OFF_BUFP);
    bf16*  bufQ  = (bf16*) (ws + OFF_BUFQ);

    const float r2_1 = (float)(0.15 * 0.15);
    const float r2_2 = (float)(0.3 * 0.3);

    // ---------------- SA module 1 (N=512 -> 256, ns=16) ----------------
    shift_kernel<512><<<192, 256, 0, stream>>>(xyz, qs1);
    fps_kernel<512, 256><<<32, 64, 0, stream>>>(qs1, idx1);
    gather_kernel<512, 256><<<96, 256, 0, stream>>>(qs1, idx1, q1c);
    ballq_kernel<512, 256, 16, 3, true><<<2048, 256, 0, stream>>>(
        xyz, q1c, xyz, r2_1, 0.15f, bufP /*x1*/, gate1);
    conv_kernel<6, 64, false><<<512, 256, 0, stream>>>(bufP, w1a, nullptr, bufQ /*y1a*/);
    stats_kernel<<<64, 256, 0, stream>>>(bufQ, 64, g1a, b1a, n1a);
    conv_kernel<64, 128, true><<<512, 256, 0, stream>>>(bufQ, w1b, n1a, bufP /*y1b*/);
    stats_kernel<<<128, 256, 0, stream>>>(bufP, 128, g1b, b1b, n1b);
    pool_kernel<16, 256, 128><<<4096, 256, 0, stream>>>(bufP, n1b, gate1, f1);

    // ---------------- SA module 2 (N=256 -> 128, ns=32) ----------------
    shift_kernel<256><<<96, 256, 0, stream>>>(q1c, qs2);
    fps_kernel<256, 128><<<32, 64, 0, stream>>>(qs2, idx2);
    gather_kernel<256, 128><<<48, 256, 0, stream>>>(qs2, idx2, q2c);
    ballq_kernel<256, 128, 32, 128, false><<<1024, 256, 0, stream>>>(
        q1c, q2c, f1, r2_2, 0.3f, bufP /*x2*/, gate2);
    conv_kernel<131, 128, false><<<512, 256, 0, stream>>>(bufP, w2a, nullptr, bufQ /*y2a*/);
    stats_kernel<<<128, 256, 0, stream>>>(bufQ, 128, g2a, b2a, n2a);
    conv_kernel<128, 256, true><<<512, 256, 0, stream>>>(bufQ, w2b, n2a, bufP /*y2b*/);
    stats_kernel<<<256, 256, 0, stream>>>(bufP, 256, g2b, b2b, n2b);
    pool_kernel<32, 128, 256><<<4096, 256, 0, stream>>>(bufP, n2b, gate2, (float*)d_out);
}

// Round 2
// 1006.300 us; speedup vs baseline: 1.4089x; 1.4089x over previous
//
#include <hip/hip_runtime.h>
#include <hip/hip_bf16.h>
#include <math.h>

// MotionNet: PointNet++-style 2-level SA.  B=32, L=16, N=512.
// M = B*npoint*nsample = 131072 for all four conv layers.
//
// R2: convs via MFMA bf16 (16x16x32), split-precision weights (hi+lo bf16),
// all big tensors in (M, C) row-major layout (coalesced everywhere),
// two-stage BN stats, LDS-transposed pool2 epilogue.
//
// Exactness discipline unchanged from the passing R1: FPS argmax + ballquery
// mask use __fmul_rn/__fadd_rn (no FMA contraction) and replicate jnp.argmax
// first-max / sort-ascending-index semantics exactly.

#define BATCH 32
#define MCOLS 131072

typedef __attribute__((ext_vector_type(8))) short short8;
typedef __attribute__((ext_vector_type(4))) short short4v;
typedef __attribute__((ext_vector_type(4))) float f32x4;

__device__ __forceinline__ float b2f(short s) {
    return __uint_as_float(((unsigned)(unsigned short)s) << 16);
}
__device__ __forceinline__ short f2b(float f) {
    __hip_bfloat16 h = __float2bfloat16(f);
    return (short)__builtin_bit_cast(unsigned short, h);
}

// ---------------------------------------------------------------- weight prep
// w (O,C) f32 -> hi/lo (O,CK) bf16 split, zero-padded cols C..CK-1.
__global__ void prep_w(const float* __restrict__ w, int O, int C, int CK,
                       short* __restrict__ hi, short* __restrict__ lo) {
    int t = blockIdx.x * 256 + threadIdx.x;
    if (t >= O * CK) return;
    int o = t / CK, c = t % CK;
    float f = (c < C) ? w[o * C + c] : 0.f;
    short h = f2b(f);
    float fh = b2f(h);
    hi[t] = h;
    lo[t] = f2b(f - fh);
}

// ---------------------------------------------------------------- shift
template<int N>
__global__ void shift_kernel(const float* __restrict__ xyz, float* __restrict__ qout) {
    int t = blockIdx.x * 256 + threadIdx.x;
    if (t >= BATCH * N * 3) return;
    int c = t % 3;
    int n = (t / 3) % N;
    int b = t / (3 * N);
    int l = b & 15;
    float v;
    if (l < 15) {
        v = xyz[((size_t)(b + 1) * N + n) * 3 + c];
    } else {
        int g0 = b - 15;
        float acc = 0.f;
        for (int i = 0; i < 15; ++i) {
            float d = __fsub_rn(xyz[((size_t)(g0 + i + 1) * N + n) * 3 + c],
                                xyz[((size_t)(g0 + i) * N + n) * 3 + c]);
            acc = __fadd_rn(acc, d);
        }
        v = __fadd_rn(xyz[((size_t)b * N + n) * 3 + c], __fdiv_rn(acc, 15.f));
    }
    qout[t] = v;
}

// ---------------------------------------------------------------- FPS
// One wave per batch; q cached in LDS as float4 (single ds_read_b128 per step).
template<int N, int NPOINT>
__global__ __launch_bounds__(64) void fps_kernel(const float* __restrict__ q,
                                                 int* __restrict__ out) {
    int b = blockIdx.x;
    int lane = threadIdx.x;
    __shared__ float4 qp[N];
    const float* qb = q + (size_t)b * N * 3;
    for (int j = lane; j < N; j += 64)
        qp[j] = make_float4(qb[j * 3 + 0], qb[j * 3 + 1], qb[j * 3 + 2], 0.f);
    __syncthreads();
    constexpr int P = N / 64;
    float mind[P];
#pragma unroll
    for (int p = 0; p < P; ++p) mind[p] = 1e10f;
    if (lane == 0) out[b * NPOINT] = 0;
    int last = 0;
    for (int s = 1; s < NPOINT; ++s) {
        float4 L = qp[last];
        float best = -1.f;
        int bj = 0x7fffffff;
#pragma unroll
        for (int p = 0; p < P; ++p) {
            int j = p * 64 + lane;
            float dx = __fsub_rn(qp[j].x, L.x);
            float dy = __fsub_rn(qp[j].y, L.y);
            float dz = __fsub_rn(qp[j].z, L.z);
            float d = __fadd_rn(__fadd_rn(__fmul_rn(dx, dx), __fmul_rn(dy, dy)),
                                __fmul_rn(dz, dz));
            float mn = fminf(mind[p], d);
            mind[p] = mn;
            if (mn > best) { best = mn; bj = j; }
        }
#pragma unroll
        for (int off = 32; off >= 1; off >>= 1) {
            float ob = __shfl_xor(best, off, 64);
            int   oj = __shfl_xor(bj,   off, 64);
            if (ob > best || (ob == best && oj < bj)) { best = ob; bj = oj; }
        }
        last = bj;
        if (lane == 0) out[b * NPOINT + s] = last;
    }
}

// ---------------------------------------------------------------- gather q
template<int N, int NPOINT>
__global__ void gather_kernel(const float* __restrict__ src, const int* __restrict__ idx,
                              float* __restrict__ dst) {
    int t = blockIdx.x * 256 + threadIdx.x;
    if (t >= BATCH * NPOINT * 3) return;
    int c = t % 3;
    int i = (t / 3) % NPOINT;
    int b = t / (3 * NPOINT);
    dst[t] = src[((size_t)b * N + idx[b * NPOINT + i]) * 3 + c];
}

// ---------------------------------------------------------------- ball query
// One wave per query.  X written (M, CK) bf16 row-major, zero-padded; gate f32.
// feats layout (B, N, CF) row-major.
template<int N, int NPOINT, int NS, int CF, int CK>
__global__ __launch_bounds__(256) void ballq_kernel(
        const float* __restrict__ xyz,    // (B,N,3)
        const float* __restrict__ qpts,   // (B,NPOINT,3)
        const float* __restrict__ feats,  // (B,N,CF)
        float r2, float radius,
        short* __restrict__ X, float* __restrict__ gate) {
    static_assert((NS & (NS - 1)) == 0, "NS pow2");
    int lane = threadIdx.x & 63;
    int wib = threadIdx.x >> 6;
    int wid = blockIdx.x * 4 + wib;
    int b = wid / NPOINT;
    int i = wid % NPOINT;
    const float* qp = qpts + ((size_t)b * NPOINT + i) * 3;
    float qx = qp[0], qy = qp[1], qz = qp[2];
    __shared__ int gsh[4][NS];
    int* gidx = gsh[wib];
    int taken = 0, first = 0;
    bool any = false;
#pragma unroll
    for (int base = 0; base < N; base += 64) {
        int j = base + lane;
        const float* p = xyz + ((size_t)b * N + j) * 3;
        float dx = __fsub_rn(qx, p[0]);
        float dy = __fsub_rn(qy, p[1]);
        float dz = __fsub_rn(qz, p[2]);
        float d2 = __fadd_rn(__fadd_rn(__fmul_rn(dx, dx), __fmul_rn(dy, dy)),
                             __fmul_rn(dz, dz));
        bool in = d2 < r2;
        unsigned long long mk = __ballot(in);
        if (!any && mk) { first = base + __builtin_ctzll(mk); any = true; }
        int cb = __builtin_popcountll(mk & ((1ull << lane) - 1ull));
        int slot = taken + cb;
        if (in && slot < NS) gidx[slot] = j;
        taken += (int)__builtin_popcountll(mk);
    }
    if (taken < NS) {
        for (int s = taken + lane; s < NS; s += 64) gidx[s] = any ? first : 0;
    }
    __syncthreads();
    int m0 = (b * NPOINT + i) * NS;
    if (lane < NS) {
        int g = gidx[lane];
        const float* p = xyz + ((size_t)b * N + g) * 3;
        float dx = (p[0] - qx) / radius;
        float dy = (p[1] - qy) / radius;
        float dz = (p[2] - qz) / radius;
        float dist = sqrtf(dx * dx + dy * dy + dz * dz);
        gate[m0 + lane] = 1.f / (1.f + expf(-dist));
    }
    for (int e = lane; e < NS * CK; e += 64) {
        int s = e / CK;
        int c = e % CK;
        int g = gidx[s];
        float v;
        if (c < 3) {
            float qc = (c == 0) ? qx : ((c == 1) ? qy : qz);
            v = (xyz[((size_t)b * N + g) * 3 + c] - qc) / radius;
        } else if (c < 3 + CF) {
            v = feats[((size_t)b * N + g) * CF + (c - 3)];
        } else {
            v = 0.f;
        }
        X[(size_t)(m0 + s) * CK + c] = f2b(v);
    }
}

// ---------------------------------------------------------------- MFMA conv
// X (M,CK) bf16 -> Y (M,O) bf16.  D = W*X^T per 16x16 tile; split weights.
// Block: 256 thr = 4 waves, 64 M-rows staged in LDS (padded stride CK+8).
// AFF: fold upstream BN affine + lrelu into the staging pass.
// Layouts (HW-verified): A/B frag: idx16=lane&15, k=quad*8+j;
//                        D: col(m)=lane&15, row(o)=quad*4+reg.
template<int CK, int O, bool AFF>
__global__ __launch_bounds__(256) void mfma_conv(
        const short* __restrict__ X, const short* __restrict__ Whi,
        const short* __restrict__ Wlo, const float* __restrict__ ss,
        short* __restrict__ Y) {
    constexpr int LR = CK + 8;           // LDS row stride (shorts), breaks pow2
    constexpr int NT = O / 16;           // o-tiles
    constexpr int CB = CK / 8;           // 16B chunks per row
    __shared__ __align__(16) short xs[64 * LR];
    __shared__ float ssl[AFF ? 2 * CK : 2];
    int tid = threadIdx.x;
    int m0 = blockIdx.x * 64;

    if constexpr (AFF) {
        for (int i = tid; i < 2 * CK; i += 256) ssl[i] = ss[i];
        __syncthreads();
    }
    for (int idx = tid; idx < 64 * CB; idx += 256) {
        int r = idx / CB;
        int col = (idx % CB) * 8;
        short8 v = *(const short8*)(X + (size_t)(m0 + r) * CK + col);
        if constexpr (AFF) {
#pragma unroll
            for (int i = 0; i < 8; ++i) {
                float f = b2f(v[i]);
                f = fmaf(f, ssl[col + i], ssl[CK + col + i]);
                f = f > 0.f ? f : 0.2f * f;
                v[i] = f2b(f);
            }
        }
        *(short8*)(xs + r * LR + col) = v;
    }
    __syncthreads();

    int lane = tid & 63;
    int wave = tid >> 6;
    int l15 = lane & 15;
    int quad = lane >> 4;
    const short* xrow = xs + (wave * 16 + l15) * LR + quad * 8;

    f32x4 acc[NT];
#pragma unroll
    for (int ot = 0; ot < NT; ++ot) acc[ot] = (f32x4){0.f, 0.f, 0.f, 0.f};

    for (int k0 = 0; k0 < CK; k0 += 32) {
        short8 bfrag = *(const short8*)(xrow + k0);
        const short* wbase = Whi + (size_t)l15 * CK + k0 + quad * 8;
        const short* lbase = Wlo + (size_t)l15 * CK + k0 + quad * 8;
#pragma unroll
        for (int ot = 0; ot < NT; ++ot) {
            short8 ah = *(const short8*)(wbase + (size_t)ot * 16 * CK);
            short8 al = *(const short8*)(lbase + (size_t)ot * 16 * CK);
            acc[ot] = __builtin_amdgcn_mfma_f32_16x16x32_bf16(ah, bfrag, acc[ot], 0, 0, 0);
            acc[ot] = __builtin_amdgcn_mfma_f32_16x16x32_bf16(al, bfrag, acc[ot], 0, 0, 0);
        }
    }
    // epilogue: lane holds D[o=quad*4+r][m=l15] for each o-tile
    size_t ybase = (size_t)(m0 + wave * 16 + l15) * O + quad * 4;
#pragma unroll
    for (int ot = 0; ot < NT; ++ot) {
        short4v pk;
#pragma unroll
        for (int r4 = 0; r4 < 4; ++r4) pk[r4] = f2b(acc[ot][r4]);
        *(short4v*)(Y + ybase + ot * 16) = pk;
    }
}

// ---------------------------------------------------------------- BN stats
// Stage 1: 256 blocks, each sums a 512-row chunk of Y (M,O) per channel.
template<int O>
__global__ __launch_bounds__(256) void stats_part(const short* __restrict__ Y,
                                                  float* __restrict__ pS,
                                                  float* __restrict__ pS2) {
    constexpr int GROUPS = 256 / O;
    constexpr int CHUNK = MCOLS / 256;
    int o = threadIdx.x % O;
    int g = threadIdx.x / O;
    int m0 = blockIdx.x * CHUNK;
    float s = 0.f, s2 = 0.f;
    for (int m = m0 + g; m < m0 + CHUNK; m += GROUPS) {
        float v = b2f(Y[(size_t)m * O + o]);
        s += v;
        s2 = fmaf(v, v, s2);
    }
    __shared__ float shs[256], shs2[256];
    shs[threadIdx.x] = s;
    shs2[threadIdx.x] = s2;
    __syncthreads();
    if (threadIdx.x < O) {
#pragma unroll
        for (int g2 = 1; g2 < GROUPS; ++g2) {
            s += shs[threadIdx.x + g2 * O];
            s2 += shs2[threadIdx.x + g2 * O];
        }
        pS[blockIdx.x * O + o] = s;
        pS2[blockIdx.x * O + o] = s2;
    }
}

// Stage 2: one block of O threads -> scale/shift.
template<int O>
__global__ void stats_fin(const float* __restrict__ pS, const float* __restrict__ pS2,
                          const float* __restrict__ gm, const float* __restrict__ bt,
                          float* __restrict__ norm) {
    int o = threadIdx.x;
    float s = 0.f, s2 = 0.f;
    for (int p = 0; p < 256; ++p) {
        s += pS[p * O + o];
        s2 += pS2[p * O + o];
    }
    const float invM = 1.f / (float)MCOLS;
    float mu = s * invM;
    float var = s2 * invM - mu * mu;
    float sc = gm[o] * rsqrtf(var + 1e-5f);
    norm[o] = sc;
    norm[O + o] = bt[o] - mu * sc;
}

// ---------------------------------------------------------------- pool 1
// Y (M,O) -> f1 (B,NPOINT,O) f32, coalesced both sides.
template<int NS, int NPOINT, int O>
__global__ __launch_bounds__(256) void pool1_kernel(
        const short* __restrict__ Y, const float* __restrict__ norm,
        const float* __restrict__ gate, float* __restrict__ out) {
    int t = blockIdx.x * 256 + threadIdx.x;     // B*NPOINT*O
    int o = t % O;
    int n = (t / O) % NPOINT;
    int b = t / (O * NPOINT);
    int m0 = (b * NPOINT + n) * NS;
    float sc = norm[o], sf = norm[O + o];
    float best = -INFINITY;
#pragma unroll
    for (int k = 0; k < NS; ++k) {
        float v = fmaf(b2f(Y[(size_t)(m0 + k) * O + o]), sc, sf);
        v = v > 0.f ? v : 0.2f * v;
        best = fmaxf(best, gate[m0 + k] * v);
    }
    out[t] = best;
}

// ---------------------------------------------------------------- pool 2
// Y (M,256) -> d_out (B,256,128) f32 via LDS transpose (coalesced writes).
// Block: (b, oc in 0..3, nc in 0..1): 64 o x 64 n tile.
__global__ __launch_bounds__(256) void pool2_kernel(
        const short* __restrict__ Y, const float* __restrict__ norm,
        const float* __restrict__ gate, float* __restrict__ out) {
    constexpr int NS = 32, NPOINT = 128, O = 256;
    int b  = blockIdx.x >> 3;
    int oc = (blockIdx.x >> 1) & 3;
    int nc = blockIdx.x & 1;
    __shared__ float trans[64][65];
    int tid = threadIdx.x;
    for (int w = 0; w < 16; ++w) {
        int idx = w * 256 + tid;
        int o_l = idx & 63;
        int n_l = idx >> 6;
        int o = oc * 64 + o_l;
        int n = nc * 64 + n_l;
        int m0 = (b * NPOINT + n) * NS;
        float sc = norm[o], sf = norm[O + o];
        float best = -INFINITY;
#pragma unroll
        for (int k = 0; k < NS; ++k) {
            float v = fmaf(b2f(Y[(size_t)(m0 + k) * O + o]), sc, sf);
            v = v > 0.f ? v : 0.2f * v;
            best = fmaxf(best, gate[m0 + k] * v);
        }
        trans[o_l][n_l] = best;
    }
    __syncthreads();
    for (int w = 0; w < 16; ++w) {
        int idx = w * 256 + tid;
        int o_l = idx >> 6;
        int n_l = idx & 63;
        out[((size_t)b * O + oc * 64 + o_l) * NPOINT + nc * 64 + n_l] = trans[o_l][n_l];
    }
}

// ---------------------------------------------------------------- launch
extern "C" void kernel_launch(void* const* d_in, const int* in_sizes, int n_in,
                              void* d_out, int out_size, void* d_ws, size_t ws_size,
                              hipStream_t stream) {
    const float* xyz = (const float*)d_in[0];
    const float* w1a = (const float*)d_in[1];
    const float* g1a = (const float*)d_in[2];
    const float* b1a = (const float*)d_in[3];
    const float* w1b = (const float*)d_in[4];
    const float* g1b = (const float*)d_in[5];
    const float* b1b = (const float*)d_in[6];
    const float* w2a = (const float*)d_in[7];
    const float* g2a = (const float*)d_in[8];
    const float* b2a = (const float*)d_in[9];
    const float* w2b = (const float*)d_in[10];
    const float* g2b = (const float*)d_in[11];
    const float* b2b = (const float*)d_in[12];

    char* ws = (char*)d_ws;
    // small persistent buffers
    constexpr size_t OFF_IDX1  = 0;         // 32768
    constexpr size_t OFF_Q1C   = 32768;     // 98304
    constexpr size_t OFF_GATE1 = 131072;    // 524288
    constexpr size_t OFF_IDX2  = 655360;    // 16384
    constexpr size_t OFF_Q2C   = 671744;    // 49152
    constexpr size_t OFF_GATE2 = 720896;    // 524288
    constexpr size_t OFF_NORM  = 1245184;   // 8192 (n1a@0,n1b@512,n2a@1536,n2b@2560)
    constexpr size_t OFF_W     = 1253376;   // 294912
    // arenas (lifetime-overlapped):
    // A (32MB): X1 -> [partials stats1a] -> Y1b -> QS2 -> Y2a -> [partials stats2b]
    // B (64MB): QS1 -> Y1a -> [partials stats1b] -> X2(40MB)+F1(@40MB) -> [partials stats2a] -> Y2b
    constexpr size_t OFF_A     = 1548288;   // 33554432
    constexpr size_t OFF_B     = 35102720;  // 67108864
    constexpr size_t OFF_F1    = OFF_B + 41943040;  // 4 MB inside B past X2
    // total 102,211,584 B

    int*   idx1  = (int*)  (ws + OFF_IDX1);
    float* q1c   = (float*)(ws + OFF_Q1C);
    float* gate1 = (float*)(ws + OFF_GATE1);
    int*   idx2  = (int*)  (ws + OFF_IDX2);
    float* q2c   = (float*)(ws + OFF_Q2C);
    float* gate2 = (float*)(ws + OFF_GATE2);
    float* n1a   = (float*)(ws + OFF_NORM);
    float* n1b   = (float*)(ws + OFF_NORM + 512);
    float* n2a   = (float*)(ws + OFF_NORM + 1536);
    float* n2b   = (float*)(ws + OFF_NORM + 2560);
    short* w1aH  = (short*)(ws + OFF_W);            // 64*32
    short* w1aL  = w1aH + 2048;
    short* w1bH  = w1aL + 2048;                     // 128*64
    short* w1bL  = w1bH + 8192;
    short* w2aH  = w1bL + 8192;                     // 128*160
    short* w2aL  = w2aH + 20480;
    short* w2bH  = w2aL + 20480;                    // 256*128
    short* w2bL  = w2bH + 32768;

    char* A = ws + OFF_A;
    char* B = ws + OFF_B;
    short* X1  = (short*)A;
    short* Y1a = (short*)B;
    short* Y1b = (short*)A;
    short* X2  = (short*)B;
    short* Y2a = (short*)A;
    short* Y2b = (short*)B;
    float* qs1 = (float*)B;
    float* qs2 = (float*)A;
    float* f1  = (float*)(ws + OFF_F1);
    float* pSA  = (float*)A;                  // partials when arena A is free
    float* pS2A = (float*)(A + 262144);
    float* pSB  = (float*)B;
    float* pS2B = (float*)(B + 262144);

    const float r2_1 = (float)(0.15 * 0.15);
    const float r2_2 = (float)(0.3 * 0.3);

    // weight prep (independent of everything else)
    prep_w<<<8,   256, 0, stream>>>(w1a, 64, 6, 32, w1aH, w1aL);
    prep_w<<<32,  256, 0, stream>>>(w1b, 128, 64, 64, w1bH, w1bL);
    prep_w<<<80,  256, 0, stream>>>(w2a, 128, 131, 160, w2aH, w2aL);
    prep_w<<<128, 256, 0, stream>>>(w2b, 256, 128, 128, w2bH, w2bL);

    // ---------------- SA module 1 (N=512 -> 256, ns=16) ----------------
    shift_kernel<512><<<192, 256, 0, stream>>>(xyz, qs1);
    fps_kernel<512, 256><<<32, 64, 0, stream>>>(qs1, idx1);
    gather_kernel<512, 256><<<96, 256, 0, stream>>>(qs1, idx1, q1c);
    ballq_kernel<512, 256, 16, 3, 32><<<2048, 256, 0, stream>>>(
        xyz, q1c, xyz, r2_1, 0.15f, X1, gate1);
    mfma_conv<32, 64, false><<<2048, 256, 0, stream>>>(X1, w1aH, w1aL, nullptr, Y1a);
    stats_part<64><<<256, 256, 0, stream>>>(Y1a, pSA, pS2A);
    stats_fin<64><<<1, 64, 0, stream>>>(pSA, pS2A, g1a, b1a, n1a);
    mfma_conv<64, 128, true><<<2048, 256, 0, stream>>>(Y1a, w1bH, w1bL, n1a, Y1b);
    stats_part<128><<<256, 256, 0, stream>>>(Y1b, pSB, pS2B);
    stats_fin<128><<<1, 128, 0, stream>>>(pSB, pS2B, g1b, b1b, n1b);
    pool1_kernel<16, 256, 128><<<4096, 256, 0, stream>>>(Y1b, n1b, gate1, f1);

    // ---------------- SA module 2 (N=256 -> 128, ns=32) ----------------
    shift_kernel<256><<<96, 256, 0, stream>>>(q1c, qs2);
    fps_kernel<256, 128><<<32, 64, 0, stream>>>(qs2, idx2);
    gather_kernel<256, 128><<<48, 256, 0, stream>>>(qs2, idx2, q2c);
    ballq_kernel<256, 128, 32, 128, 160><<<1024, 256, 0, stream>>>(
        q1c, q2c, f1, r2_2, 0.3f, X2, gate2);
    mfma_conv<160, 128, false><<<2048, 256, 0, stream>>>(X2, w2aH, w2aL, nullptr, Y2a);
    stats_part<128><<<256, 256, 0, stream>>>(Y2a, pSB, pS2B);
    stats_fin<128><<<1, 128, 0, stream>>>(pSB, pS2B, g2a, b2a, n2a);
    mfma_conv<128, 256, true><<<2048, 256, 0, stream>>>(Y2a, w2bH, w2bL, n2a, Y2b);
    stats_part<256><<<256, 256, 0, stream>>>(Y2b, pSA, pS2A);
    stats_fin<256><<<1, 256, 0, stream>>>(pSA, pS2A, g2b, b2b, n2b);
    pool2_kernel<<<256, 256, 0, stream>>>(Y2b, n2b, gate2, (float*)d_out);
}

// Round 3
// 901.300 us; speedup vs baseline: 1.5730x; 1.1165x over previous
//
#include <hip/hip_runtime.h>
#include <hip/hip_bf16.h>
#include <math.h>

// MotionNet: PointNet++-style 2-level SA.  B=32, L=16, N=512.
// M = B*npoint*nsample = 131072 for all four conv layers.
//
// R3: FPS rebuilt around DPP argmax — candidate points live in registers,
// the 64-lane argmax runs as a 6-stage v_mov_b32_dpp compare-select on a
// packed u64 key (exact f32 bits + reverse index => first-max semantics),
// and the q-gather is folded into the FPS epilogue (indices via LDS).
// Convs remain MFMA bf16 split-precision (R2).
//
// Exactness discipline: FPS argmax + ballquery mask use __fmul_rn/__fadd_rn
// (no FMA contraction); key packing preserves exact f32 comparison order and
// jnp.argmax first-max tie-breaking.

#define BATCH 32
#define MCOLS 131072

typedef __attribute__((ext_vector_type(8))) short short8;
typedef __attribute__((ext_vector_type(4))) short short4v;
typedef __attribute__((ext_vector_type(4))) float f32x4;

__device__ __forceinline__ float b2f(short s) {
    return __uint_as_float(((unsigned)(unsigned short)s) << 16);
}
__device__ __forceinline__ short f2b(float f) {
    __hip_bfloat16 h = __float2bfloat16(f);
    return (short)__builtin_bit_cast(unsigned short, h);
}

// ---------------------------------------------------------------- weight prep
__global__ void prep_w(const float* __restrict__ w, int O, int C, int CK,
                       short* __restrict__ hi, short* __restrict__ lo) {
    int t = blockIdx.x * 256 + threadIdx.x;
    if (t >= O * CK) return;
    int o = t / CK, c = t % CK;
    float f = (c < C) ? w[o * C + c] : 0.f;
    short h = f2b(f);
    float fh = b2f(h);
    hi[t] = h;
    lo[t] = f2b(f - fh);
}

// ---------------------------------------------------------------- shift
template<int N>
__global__ void shift_kernel(const float* __restrict__ xyz, float* __restrict__ qout) {
    int t = blockIdx.x * 256 + threadIdx.x;
    if (t >= BATCH * N * 3) return;
    int c = t % 3;
    int n = (t / 3) % N;
    int b = t / (3 * N);
    int l = b & 15;
    float v;
    if (l < 15) {
        v = xyz[((size_t)(b + 1) * N + n) * 3 + c];
    } else {
        int g0 = b - 15;
        float acc = 0.f;
        for (int i = 0; i < 15; ++i) {
            float d = __fsub_rn(xyz[((size_t)(g0 + i + 1) * N + n) * 3 + c],
                                xyz[((size_t)(g0 + i) * N + n) * 3 + c]);
            acc = __fadd_rn(acc, d);
        }
        v = __fadd_rn(xyz[((size_t)b * N + n) * 3 + c], __fdiv_rn(acc, 15.f));
    }
    qout[t] = v;
}

// ---------------------------------------------------------------- FPS (DPP)
// One wave per batch.  Candidates in registers; per-step 64-lane argmax via
// 6-stage DPP compare-select on key=(f32bits(mind)<<32)|(N-1-j); selected
// points written directly (gather folded in).
template<int C>
__device__ __forceinline__ void dpp_stage(unsigned& hi, unsigned& lo) {
    unsigned h2 = (unsigned)__builtin_amdgcn_update_dpp(0, (int)hi, C, 0xf, 0xf, true);
    unsigned l2 = (unsigned)__builtin_amdgcn_update_dpp(0, (int)lo, C, 0xf, 0xf, true);
    bool g = (h2 > hi) || ((h2 == hi) && (l2 > lo));
    hi = g ? h2 : hi;
    lo = g ? l2 : lo;
}

template<int N, int NPOINT>
__global__ __launch_bounds__(64) void fps_kernel(const float* __restrict__ q,
                                                 float* __restrict__ qsel) {
    int b = blockIdx.x;
    int lane = threadIdx.x;
    __shared__ float4 qp[N];
    __shared__ int sel[NPOINT];
    const float* qb = q + (size_t)b * N * 3;
    for (int j = lane; j < N; j += 64)
        qp[j] = make_float4(qb[j * 3 + 0], qb[j * 3 + 1], qb[j * 3 + 2], 0.f);
    if (lane == 0) sel[0] = 0;
    __syncthreads();
    constexpr int P = N / 64;
    float4 pt[P];
    float mind[P];
#pragma unroll
    for (int p = 0; p < P; ++p) {
        pt[p] = qp[p * 64 + lane];
        mind[p] = 1e10f;
    }
    int last = 0;
    for (int s = 1; s < NPOINT; ++s) {
        float4 L = qp[last];
        unsigned hi = 0u, lo = 0u;
#pragma unroll
        for (int p = 0; p < P; ++p) {
            float dx = __fsub_rn(pt[p].x, L.x);
            float dy = __fsub_rn(pt[p].y, L.y);
            float dz = __fsub_rn(pt[p].z, L.z);
            float d = __fadd_rn(__fadd_rn(__fmul_rn(dx, dx), __fmul_rn(dy, dy)),
                                __fmul_rn(dz, dz));
            float mn = fminf(mind[p], d);
            mind[p] = mn;
            unsigned h = __float_as_uint(mn);
            unsigned l = (unsigned)(N - 1 - (p * 64 + lane));
            bool g = (h > hi) || ((h == hi) && (l > lo));
            hi = g ? h : hi;
            lo = g ? l : lo;
        }
        dpp_stage<0x111>(hi, lo);   // row_shr:1
        dpp_stage<0x112>(hi, lo);   // row_shr:2
        dpp_stage<0x114>(hi, lo);   // row_shr:4
        dpp_stage<0x118>(hi, lo);   // row_shr:8
        dpp_stage<0x142>(hi, lo);   // row_bcast:15
        dpp_stage<0x143>(hi, lo);   // row_bcast:31
        last = (N - 1) - (int)__builtin_amdgcn_readlane((int)lo, 63);
        if (lane == 0) sel[s] = last;
    }
    __syncthreads();
    for (int i = lane; i < NPOINT; i += 64) {
        float4 Pt = qp[sel[i]];
        size_t o = ((size_t)b * NPOINT + i) * 3;
        qsel[o + 0] = Pt.x;
        qsel[o + 1] = Pt.y;
        qsel[o + 2] = Pt.z;
    }
}

// ---------------------------------------------------------------- ball query
template<int N, int NPOINT, int NS, int CF, int CK>
__global__ __launch_bounds__(256) void ballq_kernel(
        const float* __restrict__ xyz,    // (B,N,3)
        const float* __restrict__ qpts,   // (B,NPOINT,3)
        const float* __restrict__ feats,  // (B,N,CF)
        float r2, float radius,
        short* __restrict__ X, float* __restrict__ gate) {
    static_assert((NS & (NS - 1)) == 0, "NS pow2");
    int lane = threadIdx.x & 63;
    int wib = threadIdx.x >> 6;
    int wid = blockIdx.x * 4 + wib;
    int b = wid / NPOINT;
    int i = wid % NPOINT;
    const float* qp = qpts + ((size_t)b * NPOINT + i) * 3;
    float qx = qp[0], qy = qp[1], qz = qp[2];
    __shared__ int gsh[4][NS];
    int* gidx = gsh[wib];
    int taken = 0, first = 0;
    bool any = false;
#pragma unroll
    for (int base = 0; base < N; base += 64) {
        int j = base + lane;
        const float* p = xyz + ((size_t)b * N + j) * 3;
        float dx = __fsub_rn(qx, p[0]);
        float dy = __fsub_rn(qy, p[1]);
        float dz = __fsub_rn(qz, p[2]);
        float d2 = __fadd_rn(__fadd_rn(__fmul_rn(dx, dx), __fmul_rn(dy, dy)),
                             __fmul_rn(dz, dz));
        bool in = d2 < r2;
        unsigned long long mk = __ballot(in);
        if (!any && mk) { first = base + __builtin_ctzll(mk); any = true; }
        int cb = __builtin_popcountll(mk & ((1ull << lane) - 1ull));
        int slot = taken + cb;
        if (in && slot < NS) gidx[slot] = j;
        taken += (int)__builtin_popcountll(mk);
    }
    if (taken < NS) {
        for (int s = taken + lane; s < NS; s += 64) gidx[s] = any ? first : 0;
    }
    __syncthreads();
    int m0 = (b * NPOINT + i) * NS;
    if (lane < NS) {
        int g = gidx[lane];
        const float* p = xyz + ((size_t)b * N + g) * 3;
        float dx = (p[0] - qx) / radius;
        float dy = (p[1] - qy) / radius;
        float dz = (p[2] - qz) / radius;
        float dist = sqrtf(dx * dx + dy * dy + dz * dz);
        gate[m0 + lane] = 1.f / (1.f + expf(-dist));
    }
    for (int e = lane; e < NS * CK; e += 64) {
        int s = e / CK;
        int c = e % CK;
        int g = gidx[s];
        float v;
        if (c < 3) {
            float qc = (c == 0) ? qx : ((c == 1) ? qy : qz);
            v = (xyz[((size_t)b * N + g) * 3 + c] - qc) / radius;
        } else if (c < 3 + CF) {
            v = feats[((size_t)b * N + g) * CF + (c - 3)];
        } else {
            v = 0.f;
        }
        X[(size_t)(m0 + s) * CK + c] = f2b(v);
    }
}

// ---------------------------------------------------------------- MFMA conv
// X (M,CK) bf16 -> Y (M,O) bf16.  Split weights hi+lo; 64 M-rows per block.
template<int CK, int O, bool AFF>
__global__ __launch_bounds__(256) void mfma_conv(
        const short* __restrict__ X, const short* __restrict__ Whi,
        const short* __restrict__ Wlo, const float* __restrict__ ss,
        short* __restrict__ Y) {
    constexpr int LR = CK + 8;
    constexpr int NT = O / 16;
    constexpr int CB = CK / 8;
    __shared__ __align__(16) short xs[64 * LR];
    __shared__ float ssl[AFF ? 2 * CK : 2];
    int tid = threadIdx.x;
    int m0 = blockIdx.x * 64;

    if constexpr (AFF) {
        for (int i = tid; i < 2 * CK; i += 256) ssl[i] = ss[i];
        __syncthreads();
    }
    for (int idx = tid; idx < 64 * CB; idx += 256) {
        int r = idx / CB;
        int col = (idx % CB) * 8;
        short8 v = *(const short8*)(X + (size_t)(m0 + r) * CK + col);
        if constexpr (AFF) {
#pragma unroll
            for (int i = 0; i < 8; ++i) {
                float f = b2f(v[i]);
                f = fmaf(f, ssl[col + i], ssl[CK + col + i]);
                f = f > 0.f ? f : 0.2f * f;
                v[i] = f2b(f);
            }
        }
        *(short8*)(xs + r * LR + col) = v;
    }
    __syncthreads();

    int lane = tid & 63;
    int wave = tid >> 6;
    int l15 = lane & 15;
    int quad = lane >> 4;
    const short* xrow = xs + (wave * 16 + l15) * LR + quad * 8;

    f32x4 acc[NT];
#pragma unroll
    for (int ot = 0; ot < NT; ++ot) acc[ot] = (f32x4){0.f, 0.f, 0.f, 0.f};

    for (int k0 = 0; k0 < CK; k0 += 32) {
        short8 bfrag = *(const short8*)(xrow + k0);
        const short* wbase = Whi + (size_t)l15 * CK + k0 + quad * 8;
        const short* lbase = Wlo + (size_t)l15 * CK + k0 + quad * 8;
#pragma unroll
        for (int ot = 0; ot < NT; ++ot) {
            short8 ah = *(const short8*)(wbase + (size_t)ot * 16 * CK);
            short8 al = *(const short8*)(lbase + (size_t)ot * 16 * CK);
            acc[ot] = __builtin_amdgcn_mfma_f32_16x16x32_bf16(ah, bfrag, acc[ot], 0, 0, 0);
            acc[ot] = __builtin_amdgcn_mfma_f32_16x16x32_bf16(al, bfrag, acc[ot], 0, 0, 0);
        }
    }
    size_t ybase = (size_t)(m0 + wave * 16 + l15) * O + quad * 4;
#pragma unroll
    for (int ot = 0; ot < NT; ++ot) {
        short4v pk;
#pragma unroll
        for (int r4 = 0; r4 < 4; ++r4) pk[r4] = f2b(acc[ot][r4]);
        *(short4v*)(Y + ybase + ot * 16) = pk;
    }
}

// ---------------------------------------------------------------- BN stats
template<int O>
__global__ __launch_bounds__(256) void stats_part(const short* __restrict__ Y,
                                                  float* __restrict__ pS,
                                                  float* __restrict__ pS2) {
    constexpr int GROUPS = 256 / O;
    constexpr int CHUNK = MCOLS / 256;
    int o = threadIdx.x % O;
    int g = threadIdx.x / O;
    int m0 = blockIdx.x * CHUNK;
    float s = 0.f, s2 = 0.f;
    for (int m = m0 + g; m < m0 + CHUNK; m += GROUPS) {
        float v = b2f(Y[(size_t)m * O + o]);
        s += v;
        s2 = fmaf(v, v, s2);
    }
    __shared__ float shs[256], shs2[256];
    shs[threadIdx.x] = s;
    shs2[threadIdx.x] = s2;
    __syncthreads();
    if (threadIdx.x < O) {
#pragma unroll
        for (int g2 = 1; g2 < GROUPS; ++g2) {
            s += shs[threadIdx.x + g2 * O];
            s2 += shs2[threadIdx.x + g2 * O];
        }
        pS[blockIdx.x * O + o] = s;
        pS2[blockIdx.x * O + o] = s2;
    }
}

template<int O>
__global__ void stats_fin(const float* __restrict__ pS, const float* __restrict__ pS2,
                          const float* __restrict__ gm, const float* __restrict__ bt,
                          float* __restrict__ norm) {
    int o = threadIdx.x;
    float s = 0.f, s2 = 0.f;
    for (int p = 0; p < 256; ++p) {
        s += pS[p * O + o];
        s2 += pS2[p * O + o];
    }
    const float invM = 1.f / (float)MCOLS;
    float mu = s * invM;
    float var = s2 * invM - mu * mu;
    float sc = gm[o] * rsqrtf(var + 1e-5f);
    norm[o] = sc;
    norm[O + o] = bt[o] - mu * sc;
}

// ---------------------------------------------------------------- pool 1
template<int NS, int NPOINT, int O>
__global__ __launch_bounds__(256) void pool1_kernel(
        const short* __restrict__ Y, const float* __restrict__ norm,
        const float* __restrict__ gate, float* __restrict__ out) {
    int t = blockIdx.x * 256 + threadIdx.x;
    int o = t % O;
    int n = (t / O) % NPOINT;
    int b = t / (O * NPOINT);
    int m0 = (b * NPOINT + n) * NS;
    float sc = norm[o], sf = norm[O + o];
    float best = -INFINITY;
#pragma unroll
    for (int k = 0; k < NS; ++k) {
        float v = fmaf(b2f(Y[(size_t)(m0 + k) * O + o]), sc, sf);
        v = v > 0.f ? v : 0.2f * v;
        best = fmaxf(best, gate[m0 + k] * v);
    }
    out[t] = best;
}

// ---------------------------------------------------------------- pool 2
__global__ __launch_bounds__(256) void pool2_kernel(
        const short* __restrict__ Y, const float* __restrict__ norm,
        const float* __restrict__ gate, float* __restrict__ out) {
    constexpr int NS = 32, NPOINT = 128, O = 256;
    int b  = blockIdx.x >> 3;
    int oc = (blockIdx.x >> 1) & 3;
    int nc = blockIdx.x & 1;
    __shared__ float trans[64][65];
    int tid = threadIdx.x;
    for (int w = 0; w < 16; ++w) {
        int idx = w * 256 + tid;
        int o_l = idx & 63;
        int n_l = idx >> 6;
        int o = oc * 64 + o_l;
        int n = nc * 64 + n_l;
        int m0 = (b * NPOINT + n) * NS;
        float sc = norm[o], sf = norm[O + o];
        float best = -INFINITY;
#pragma unroll
        for (int k = 0; k < NS; ++k) {
            float v = fmaf(b2f(Y[(size_t)(m0 + k) * O + o]), sc, sf);
            v = v > 0.f ? v : 0.2f * v;
            best = fmaxf(best, gate[m0 + k] * v);
        }
        trans[o_l][n_l] = best;
    }
    __syncthreads();
    for (int w = 0; w < 16; ++w) {
        int idx = w * 256 + tid;
        int o_l = idx >> 6;
        int n_l = idx & 63;
        out[((size_t)b * O + oc * 64 + o_l) * NPOINT + nc * 64 + n_l] = trans[o_l][n_l];
    }
}

// ---------------------------------------------------------------- launch
extern "C" void kernel_launch(void* const* d_in, const int* in_sizes, int n_in,
                              void* d_out, int out_size, void* d_ws, size_t ws_size,
                              hipStream_t stream) {
    const float* xyz = (const float*)d_in[0];
    const float* w1a = (const float*)d_in[1];
    const float* g1a = (const float*)d_in[2];
    const float* b1a = (const float*)d_in[3];
    const float* w1b = (const float*)d_in[4];
    const float* g1b = (const float*)d_in[5];
    const float* b1b = (const float*)d_in[6];
    const float* w2a = (const float*)d_in[7];
    const float* g2a = (const float*)d_in[8];
    const float* b2a = (const float*)d_in[9];
    const float* w2b = (const float*)d_in[10];
    const float* g2b = (const float*)d_in[11];
    const float* b2b = (const float*)d_in[12];

    char* ws = (char*)d_ws;
    constexpr size_t OFF_Q1C   = 32768;     // 98304
    constexpr size_t OFF_GATE1 = 131072;    // 524288
    constexpr size_t OFF_Q2C   = 671744;    // 49152
    constexpr size_t OFF_GATE2 = 720896;    // 524288
    constexpr size_t OFF_NORM  = 1245184;   // 8192
    constexpr size_t OFF_W     = 1253376;   // 294912
    // arenas (lifetime-overlapped):
    // A (32MB): X1 -> [partials 1a] -> Y1b -> QS2 -> Y2a -> [partials 2b]
    // B (64MB): QS1 -> Y1a -> [partials 1b] -> X2(40MB)+F1(@40MB) -> [partials 2a] -> Y2b
    constexpr size_t OFF_A     = 1548288;   // 33554432
    constexpr size_t OFF_B     = 35102720;  // 67108864
    constexpr size_t OFF_F1    = OFF_B + 41943040;

    float* q1c   = (float*)(ws + OFF_Q1C);
    float* gate1 = (float*)(ws + OFF_GATE1);
    float* q2c   = (float*)(ws + OFF_Q2C);
    float* gate2 = (float*)(ws + OFF_GATE2);
    float* n1a   = (float*)(ws + OFF_NORM);
    float* n1b   = (float*)(ws + OFF_NORM + 512);
    float* n2a   = (float*)(ws + OFF_NORM + 1536);
    float* n2b   = (float*)(ws + OFF_NORM + 2560);
    short* w1aH  = (short*)(ws + OFF_W);
    short* w1aL  = w1aH + 2048;
    short* w1bH  = w1aL + 2048;
    short* w1bL  = w1bH + 8192;
    short* w2aH  = w1bL + 8192;
    short* w2aL  = w2aH + 20480;
    short* w2bH  = w2aL + 20480;
    short* w2bL  = w2bH + 32768;

    char* A = ws + OFF_A;
    char* B = ws + OFF_B;
    short* X1  = (short*)A;
    short* Y1a = (short*)B;
    short* Y1b = (short*)A;
    short* X2  = (short*)B;
    short* Y2a = (short*)A;
    short* Y2b = (short*)B;
    float* qs1 = (float*)B;
    float* qs2 = (float*)A;
    float* f1  = (float*)(ws + OFF_F1);
    float* pSA  = (float*)A;
    float* pS2A = (float*)(A + 262144);
    float* pSB  = (float*)B;
    float* pS2B = (float*)(B + 262144);

    const float r2_1 = (float)(0.15 * 0.15);
    const float r2_2 = (float)(0.3 * 0.3);

    prep_w<<<8,   256, 0, stream>>>(w1a, 64, 6, 32, w1aH, w1aL);
    prep_w<<<32,  256, 0, stream>>>(w1b, 128, 64, 64, w1bH, w1bL);
    prep_w<<<80,  256, 0, stream>>>(w2a, 128, 131, 160, w2aH, w2aL);
    prep_w<<<128, 256, 0, stream>>>(w2b, 256, 128, 128, w2bH, w2bL);

    // ---------------- SA module 1 (N=512 -> 256, ns=16) ----------------
    shift_kernel<512><<<192, 256, 0, stream>>>(xyz, qs1);
    fps_kernel<512, 256><<<32, 64, 0, stream>>>(qs1, q1c);
    ballq_kernel<512, 256, 16, 3, 32><<<2048, 256, 0, stream>>>(
        xyz, q1c, xyz, r2_1, 0.15f, X1, gate1);
    mfma_conv<32, 64, false><<<2048, 256, 0, stream>>>(X1, w1aH, w1aL, nullptr, Y1a);
    stats_part<64><<<256, 256, 0, stream>>>(Y1a, pSA, pS2A);
    stats_fin<64><<<1, 64, 0, stream>>>(pSA, pS2A, g1a, b1a, n1a);
    mfma_conv<64, 128, true><<<2048, 256, 0, stream>>>(Y1a, w1bH, w1bL, n1a, Y1b);
    stats_part<128><<<256, 256, 0, stream>>>(Y1b, pSB, pS2B);
    stats_fin<128><<<1, 128, 0, stream>>>(pSB, pS2B, g1b, b1b, n1b);
    pool1_kernel<16, 256, 128><<<4096, 256, 0, stream>>>(Y1b, n1b, gate1, f1);

    // ---------------- SA module 2 (N=256 -> 128, ns=32) ----------------
    shift_kernel<256><<<96, 256, 0, stream>>>(q1c, qs2);
    fps_kernel<256, 128><<<32, 64, 0, stream>>>(qs2, q2c);
    ballq_kernel<256, 128, 32, 128, 160><<<1024, 256, 0, stream>>>(
        q1c, q2c, f1, r2_2, 0.3f, X2, gate2);
    mfma_conv<160, 128, false><<<2048, 256, 0, stream>>>(X2, w2aH, w2aL, nullptr, Y2a);
    stats_part<128><<<256, 256, 0, stream>>>(Y2a, pSB, pS2B);
    stats_fin<128><<<1, 128, 0, stream>>>(pSB, pS2B, g2a, b2a, n2a);
    mfma_conv<128, 256, true><<<2048, 256, 0, stream>>>(Y2a, w2bH, w2bL, n2a, Y2b);
    stats_part<256><<<256, 256, 0, stream>>>(Y2b, pSA, pS2A);
    stats_fin<256><<<1, 256, 0, stream>>>(pSA, pS2A, g2b, b2b, n2b);
    pool2_kernel<<<256, 256, 0, stream>>>(Y2b, n2b, gate2, (float*)d_out);
}

// Round 4
// 452.418 us; speedup vs baseline: 3.1338x; 1.9922x over previous
//
#include <hip/hip_runtime.h>
#include <hip/hip_bf16.h>
#include <math.h>

// MotionNet: PointNet++-style 2-level SA.  B=32, L=16, N=512.
// M = B*npoint*nsample = 131072 for all four conv layers.
//
// R4: conv weights pre-packed fragment-major, staged per-K-chunk into LDS
// (coalesced, shared by all 4 waves) — kills the uncoalesced per-lane W
// gather that left every pipe <8% busy in R3.  BN stats fused into the conv
// epilogue (DPP row-reduce of f32 accs -> per-block partials -> per-channel
// finalize), deleting the stats_part passes over Y.
//
// Accumulation order per (m,o): kc ascending, hi-MFMA then lo-MFMA — bit-
// identical to the passing R3.  FPS/ballquery exactness discipline unchanged.

#define BATCH 32
#define MCOLS 131072
#define CGRID 2048            // MCOLS / 64 conv blocks

typedef __attribute__((ext_vector_type(8))) short short8;
typedef __attribute__((ext_vector_type(4))) short short4v;
typedef __attribute__((ext_vector_type(4))) float f32x4;

__device__ __forceinline__ float b2f(short s) {
    return __uint_as_float(((unsigned)(unsigned short)s) << 16);
}
__device__ __forceinline__ short f2b(float f) {
    __hip_bfloat16 h = __float2bfloat16(f);
    return (short)__builtin_bit_cast(unsigned short, h);
}
__device__ __forceinline__ float dpp_row16_sum(float v) {
    // sum over 16-lane rows; result valid in lane with (lane&15)==15
    int x;
    x = __builtin_amdgcn_update_dpp(0, __float_as_int(v), 0x111, 0xf, 0xf, true);
    v += __int_as_float(x);
    x = __builtin_amdgcn_update_dpp(0, __float_as_int(v), 0x112, 0xf, 0xf, true);
    v += __int_as_float(x);
    x = __builtin_amdgcn_update_dpp(0, __float_as_int(v), 0x114, 0xf, 0xf, true);
    v += __int_as_float(x);
    x = __builtin_amdgcn_update_dpp(0, __float_as_int(v), 0x118, 0xf, 0xf, true);
    v += __int_as_float(x);
    return v;
}

// ---------------------------------------------------------------- weight prep
// w (O,C) f32 -> hi/lo packed fragment-major, zero-padded cols C..CK-1.
// Element (o,c): ot=o>>4, l15=o&15, kc=c>>5, quad=(c&31)>>3, j=c&7,
// lane=quad*16+l15; flat = ((kc*NT+ot)*64+lane)*8+j.
__global__ void prep_w(const float* __restrict__ w, int O, int C, int CK,
                       short* __restrict__ hi, short* __restrict__ lo) {
    int t = blockIdx.x * 256 + threadIdx.x;
    if (t >= O * CK) return;
    int o = t / CK, c = t % CK;
    float f = (c < C) ? w[o * C + c] : 0.f;
    short h = f2b(f);
    float fh = b2f(h);
    int NT = O >> 4;
    int ot = o >> 4, l15 = o & 15;
    int kc = c >> 5, quad = (c & 31) >> 3, j = c & 7;
    size_t idx = (((size_t)kc * NT + ot) * 64 + quad * 16 + l15) * 8 + j;
    hi[idx] = h;
    lo[idx] = f2b(f - fh);
}

// ---------------------------------------------------------------- shift
template<int N>
__global__ void shift_kernel(const float* __restrict__ xyz, float* __restrict__ qout) {
    int t = blockIdx.x * 256 + threadIdx.x;
    if (t >= BATCH * N * 3) return;
    int c = t % 3;
    int n = (t / 3) % N;
    int b = t / (3 * N);
    int l = b & 15;
    float v;
    if (l < 15) {
        v = xyz[((size_t)(b + 1) * N + n) * 3 + c];
    } else {
        int g0 = b - 15;
        float acc = 0.f;
        for (int i = 0; i < 15; ++i) {
            float d = __fsub_rn(xyz[((size_t)(g0 + i + 1) * N + n) * 3 + c],
                                xyz[((size_t)(g0 + i) * N + n) * 3 + c]);
            acc = __fadd_rn(acc, d);
        }
        v = __fadd_rn(xyz[((size_t)b * N + n) * 3 + c], __fdiv_rn(acc, 15.f));
    }
    qout[t] = v;
}

// ---------------------------------------------------------------- FPS (DPP)
template<int C>
__device__ __forceinline__ void dpp_stage(unsigned& hi, unsigned& lo) {
    unsigned h2 = (unsigned)__builtin_amdgcn_update_dpp(0, (int)hi, C, 0xf, 0xf, true);
    unsigned l2 = (unsigned)__builtin_amdgcn_update_dpp(0, (int)lo, C, 0xf, 0xf, true);
    bool g = (h2 > hi) || ((h2 == hi) && (l2 > lo));
    hi = g ? h2 : hi;
    lo = g ? l2 : lo;
}

template<int N, int NPOINT>
__global__ __launch_bounds__(64) void fps_kernel(const float* __restrict__ q,
                                                 float* __restrict__ qsel) {
    int b = blockIdx.x;
    int lane = threadIdx.x;
    __shared__ float4 qp[N];
    __shared__ int sel[NPOINT];
    const float* qb = q + (size_t)b * N * 3;
    for (int j = lane; j < N; j += 64)
        qp[j] = make_float4(qb[j * 3 + 0], qb[j * 3 + 1], qb[j * 3 + 2], 0.f);
    if (lane == 0) sel[0] = 0;
    __syncthreads();
    constexpr int P = N / 64;
    float4 pt[P];
    float mind[P];
#pragma unroll
    for (int p = 0; p < P; ++p) {
        pt[p] = qp[p * 64 + lane];
        mind[p] = 1e10f;
    }
    int last = 0;
    for (int s = 1; s < NPOINT; ++s) {
        float4 L = qp[last];
        unsigned hi = 0u, lo = 0u;
#pragma unroll
        for (int p = 0; p < P; ++p) {
            float dx = __fsub_rn(pt[p].x, L.x);
            float dy = __fsub_rn(pt[p].y, L.y);
            float dz = __fsub_rn(pt[p].z, L.z);
            float d = __fadd_rn(__fadd_rn(__fmul_rn(dx, dx), __fmul_rn(dy, dy)),
                                __fmul_rn(dz, dz));
            float mn = fminf(mind[p], d);
            mind[p] = mn;
            unsigned h = __float_as_uint(mn);
            unsigned l = (unsigned)(N - 1 - (p * 64 + lane));
            bool g = (h > hi) || ((h == hi) && (l > lo));
            hi = g ? h : hi;
            lo = g ? l : lo;
        }
        dpp_stage<0x111>(hi, lo);
        dpp_stage<0x112>(hi, lo);
        dpp_stage<0x114>(hi, lo);
        dpp_stage<0x118>(hi, lo);
        dpp_stage<0x142>(hi, lo);
        dpp_stage<0x143>(hi, lo);
        last = (N - 1) - (int)__builtin_amdgcn_readlane((int)lo, 63);
        if (lane == 0) sel[s] = last;
    }
    __syncthreads();
    for (int i = lane; i < NPOINT; i += 64) {
        float4 Pt = qp[sel[i]];
        size_t o = ((size_t)b * NPOINT + i) * 3;
        qsel[o + 0] = Pt.x;
        qsel[o + 1] = Pt.y;
        qsel[o + 2] = Pt.z;
    }
}

// ---------------------------------------------------------------- ball query
template<int N, int NPOINT, int NS, int CF, int CK>
__global__ __launch_bounds__(256) void ballq_kernel(
        const float* __restrict__ xyz,    // (B,N,3)
        const float* __restrict__ qpts,   // (B,NPOINT,3)
        const float* __restrict__ feats,  // (B,N,CF)
        float r2, float radius,
        short* __restrict__ X, float* __restrict__ gate) {
    static_assert((NS & (NS - 1)) == 0, "NS pow2");
    int lane = threadIdx.x & 63;
    int wib = threadIdx.x >> 6;
    int wid = blockIdx.x * 4 + wib;
    int b = wid / NPOINT;
    int i = wid % NPOINT;
    const float* qp = qpts + ((size_t)b * NPOINT + i) * 3;
    float qx = qp[0], qy = qp[1], qz = qp[2];
    __shared__ int gsh[4][NS];
    int* gidx = gsh[wib];
    int taken = 0, first = 0;
    bool any = false;
#pragma unroll
    for (int base = 0; base < N; base += 64) {
        int j = base + lane;
        const float* p = xyz + ((size_t)b * N + j) * 3;
        float dx = __fsub_rn(qx, p[0]);
        float dy = __fsub_rn(qy, p[1]);
        float dz = __fsub_rn(qz, p[2]);
        float d2 = __fadd_rn(__fadd_rn(__fmul_rn(dx, dx), __fmul_rn(dy, dy)),
                             __fmul_rn(dz, dz));
        bool in = d2 < r2;
        unsigned long long mk = __ballot(in);
        if (!any && mk) { first = base + __builtin_ctzll(mk); any = true; }
        int cb = __builtin_popcountll(mk & ((1ull << lane) - 1ull));
        int slot = taken + cb;
        if (in && slot < NS) gidx[slot] = j;
        taken += (int)__builtin_popcountll(mk);
    }
    if (taken < NS) {
        for (int s = taken + lane; s < NS; s += 64) gidx[s] = any ? first : 0;
    }
    __syncthreads();
    int m0 = (b * NPOINT + i) * NS;
    if (lane < NS) {
        int g = gidx[lane];
        const float* p = xyz + ((size_t)b * N + g) * 3;
        float dx = (p[0] - qx) / radius;
        float dy = (p[1] - qy) / radius;
        float dz = (p[2] - qz) / radius;
        float dist = sqrtf(dx * dx + dy * dy + dz * dz);
        gate[m0 + lane] = 1.f / (1.f + expf(-dist));
    }
    for (int e = lane; e < NS * CK; e += 64) {
        int s = e / CK;
        int c = e % CK;
        int g = gidx[s];
        float v;
        if (c < 3) {
            float qc = (c == 0) ? qx : ((c == 1) ? qy : qz);
            v = (xyz[((size_t)b * N + g) * 3 + c] - qc) / radius;
        } else if (c < 3 + CF) {
            v = feats[((size_t)b * N + g) * CF + (c - 3)];
        } else {
            v = 0.f;
        }
        X[(size_t)(m0 + s) * CK + c] = f2b(v);
    }
}

// ---------------------------------------------------------------- MFMA conv
// X (M,CK) bf16 -> Y (M,O) bf16.  W chunks staged in LDS per k-step
// (fragment-major, coalesced, shared by all 4 waves).  Waves split O.
// Fused BN stats: f32 acc sums -> DPP row16 reduce -> per-block partials.
template<int CK, int O, bool AFF>
__global__ __launch_bounds__(256, 3) void mfma_conv(
        const short* __restrict__ X, const short* __restrict__ Whi,
        const short* __restrict__ Wlo, const float* __restrict__ ss,
        short* __restrict__ Y, float* __restrict__ pS, float* __restrict__ pS2) {
    constexpr int KC = CK / 32;          // k-chunks
    constexpr int NT = O / 16;           // o-tiles per block
    constexpr int OW = NT / 4;           // o-tiles per wave
    constexpr int LR = CK + 8;           // X LDS row stride (shorts)
    constexpr int CB = CK / 8;
    __shared__ __align__(16) short xs[64 * LR];
    __shared__ __align__(16) short wh[NT * 512];   // one k-chunk of Whi
    __shared__ __align__(16) short wl[NT * 512];
    __shared__ float ssl[AFF ? 2 * CK : 1];
    __shared__ float sblk[O], s2blk[O];
    int tid = threadIdx.x;
    int m0 = blockIdx.x * 64;

    if constexpr (AFF) {
        for (int i = tid; i < 2 * CK; i += 256) ssl[i] = ss[i];
        __syncthreads();
    }
    // stage X tile (fused upstream affine+lrelu)
    for (int idx = tid; idx < 64 * CB; idx += 256) {
        int r = idx / CB;
        int col = (idx % CB) * 8;
        short8 v = *(const short8*)(X + (size_t)(m0 + r) * CK + col);
        if constexpr (AFF) {
#pragma unroll
            for (int i = 0; i < 8; ++i) {
                float f = b2f(v[i]);
                f = fmaf(f, ssl[col + i], ssl[CK + col + i]);
                f = f > 0.f ? f : 0.2f * f;
                v[i] = f2b(f);
            }
        }
        *(short8*)(xs + r * LR + col) = v;
    }

    int lane = tid & 63;
    int wave = tid >> 6;
    int l15 = lane & 15;
    int quad = lane >> 4;
    int obase = wave * OW * 16;

    f32x4 acc[4][OW];
#pragma unroll
    for (int mt = 0; mt < 4; ++mt)
#pragma unroll
        for (int ot = 0; ot < OW; ++ot) acc[mt][ot] = (f32x4){0.f, 0.f, 0.f, 0.f};

    for (int kc = 0; kc < KC; ++kc) {
        __syncthreads();                       // W buffer safe to overwrite
        {   // stage this k-chunk of W (coalesced 16B, shared by block)
            const short8* gH = (const short8*)Whi + (size_t)kc * NT * 64;
            const short8* gL = (const short8*)Wlo + (size_t)kc * NT * 64;
            short8* lH = (short8*)wh;
            short8* lL = (short8*)wl;
            for (int i = tid; i < NT * 64; i += 256) { lH[i] = gH[i]; lL[i] = gL[i]; }
        }
        __syncthreads();
        short8 bf[4];
#pragma unroll
        for (int mt = 0; mt < 4; ++mt)
            bf[mt] = *(const short8*)(xs + (mt * 16 + l15) * LR + kc * 32 + quad * 8);
#pragma unroll
        for (int ot = 0; ot < OW; ++ot) {
            short8 ah = ((const short8*)wh)[(wave * OW + ot) * 64 + lane];
            short8 al = ((const short8*)wl)[(wave * OW + ot) * 64 + lane];
#pragma unroll
            for (int mt = 0; mt < 4; ++mt) {
                acc[mt][ot] = __builtin_amdgcn_mfma_f32_16x16x32_bf16(ah, bf[mt], acc[mt][ot], 0, 0, 0);
                acc[mt][ot] = __builtin_amdgcn_mfma_f32_16x16x32_bf16(al, bf[mt], acc[mt][ot], 0, 0, 0);
            }
        }
    }

    // epilogue: Y write (lane holds D[o=quad*4+r][m=l15])
#pragma unroll
    for (int mt = 0; mt < 4; ++mt) {
        size_t ybase = (size_t)(m0 + mt * 16 + l15) * O + obase + quad * 4;
#pragma unroll
        for (int ot = 0; ot < OW; ++ot) {
            short4v pk;
#pragma unroll
            for (int r4 = 0; r4 < 4; ++r4) pk[r4] = f2b(acc[mt][ot][r4]);
            *(short4v*)(Y + ybase + ot * 16) = pk;
        }
    }
    // fused stats: per-channel partial sums from f32 accs
#pragma unroll
    for (int ot = 0; ot < OW; ++ot) {
#pragma unroll
        for (int r4 = 0; r4 < 4; ++r4) {
            float s = 0.f, s2 = 0.f;
#pragma unroll
            for (int mt = 0; mt < 4; ++mt) {
                float v = acc[mt][ot][r4];
                s += v;
                s2 = fmaf(v, v, s2);
            }
            s = dpp_row16_sum(s);
            s2 = dpp_row16_sum(s2);
            if (l15 == 15) {
                int o = obase + ot * 16 + quad * 4 + r4;
                sblk[o] = s;
                s2blk[o] = s2;
            }
        }
    }
    __syncthreads();
    for (int o = tid; o < O; o += 256) {
        pS [(size_t)o * CGRID + blockIdx.x] = sblk[o];
        pS2[(size_t)o * CGRID + blockIdx.x] = s2blk[o];
    }
}

// ---------------------------------------------------------------- BN finalize
// One block per channel: reduce CGRID partials -> scale/shift.
template<int O>
__global__ __launch_bounds__(256) void stats_fin(
        const float* __restrict__ pS, const float* __restrict__ pS2,
        const float* __restrict__ gm, const float* __restrict__ bt,
        float* __restrict__ norm) {
    int o = blockIdx.x;
    float s = 0.f, s2 = 0.f;
    for (int p = threadIdx.x; p < CGRID; p += 256) {
        s += pS[(size_t)o * CGRID + p];
        s2 += pS2[(size_t)o * CGRID + p];
    }
#pragma unroll
    for (int off = 32; off >= 1; off >>= 1) {
        s  += __shfl_xor(s,  off, 64);
        s2 += __shfl_xor(s2, off, 64);
    }
    __shared__ float sh[8];
    int wid = threadIdx.x >> 6;
    if ((threadIdx.x & 63) == 0) { sh[wid] = s; sh[4 + wid] = s2; }
    __syncthreads();
    if (threadIdx.x == 0) {
        float S  = sh[0] + sh[1] + sh[2] + sh[3];
        float S2 = sh[4] + sh[5] + sh[6] + sh[7];
        const float invM = 1.f / (float)MCOLS;
        float mu = S * invM;
        float var = S2 * invM - mu * mu;
        float sc = gm[o] * rsqrtf(var + 1e-5f);
        norm[o] = sc;
        norm[O + o] = bt[o] - mu * sc;
    }
}

// ---------------------------------------------------------------- pool 1
template<int NS, int NPOINT, int O>
__global__ __launch_bounds__(256) void pool1_kernel(
        const short* __restrict__ Y, const float* __restrict__ norm,
        const float* __restrict__ gate, float* __restrict__ out) {
    int t = blockIdx.x * 256 + threadIdx.x;
    int o = t % O;
    int n = (t / O) % NPOINT;
    int b = t / (O * NPOINT);
    int m0 = (b * NPOINT + n) * NS;
    float sc = norm[o], sf = norm[O + o];
    float best = -INFINITY;
#pragma unroll
    for (int k = 0; k < NS; ++k) {
        float v = fmaf(b2f(Y[(size_t)(m0 + k) * O + o]), sc, sf);
        v = v > 0.f ? v : 0.2f * v;
        best = fmaxf(best, gate[m0 + k] * v);
    }
    out[t] = best;
}

// ---------------------------------------------------------------- pool 2
__global__ __launch_bounds__(256) void pool2_kernel(
        const short* __restrict__ Y, const float* __restrict__ norm,
        const float* __restrict__ gate, float* __restrict__ out) {
    constexpr int NS = 32, NPOINT = 128, O = 256;
    int b  = blockIdx.x >> 3;
    int oc = (blockIdx.x >> 1) & 3;
    int nc = blockIdx.x & 1;
    __shared__ float trans[64][65];
    int tid = threadIdx.x;
    for (int w = 0; w < 16; ++w) {
        int idx = w * 256 + tid;
        int o_l = idx & 63;
        int n_l = idx >> 6;
        int o = oc * 64 + o_l;
        int n = nc * 64 + n_l;
        int m0 = (b * NPOINT + n) * NS;
        float sc = norm[o], sf = norm[O + o];
        float best = -INFINITY;
#pragma unroll
        for (int k = 0; k < NS; ++k) {
            float v = fmaf(b2f(Y[(size_t)(m0 + k) * O + o]), sc, sf);
            v = v > 0.f ? v : 0.2f * v;
            best = fmaxf(best, gate[m0 + k] * v);
        }
        trans[o_l][n_l] = best;
    }
    __syncthreads();
    for (int w = 0; w < 16; ++w) {
        int idx = w * 256 + tid;
        int o_l = idx >> 6;
        int n_l = idx & 63;
        out[((size_t)b * O + oc * 64 + o_l) * NPOINT + nc * 64 + n_l] = trans[o_l][n_l];
    }
}

// ---------------------------------------------------------------- launch
extern "C" void kernel_launch(void* const* d_in, const int* in_sizes, int n_in,
                              void* d_out, int out_size, void* d_ws, size_t ws_size,
                              hipStream_t stream) {
    const float* xyz = (const float*)d_in[0];
    const float* w1a = (const float*)d_in[1];
    const float* g1a = (const float*)d_in[2];
    const float* b1a = (const float*)d_in[3];
    const float* w1b = (const float*)d_in[4];
    const float* g1b = (const float*)d_in[5];
    const float* b1b = (const float*)d_in[6];
    const float* w2a = (const float*)d_in[7];
    const float* g2a = (const float*)d_in[8];
    const float* b2a = (const float*)d_in[9];
    const float* w2b = (const float*)d_in[10];
    const float* g2b = (const float*)d_in[11];
    const float* b2b = (const float*)d_in[12];

    char* ws = (char*)d_ws;
    constexpr size_t OFF_Q1C   = 0;          // 98304
    constexpr size_t OFF_GATE1 = 98304;      // 524288
    constexpr size_t OFF_Q2C   = 622592;     // 49152
    constexpr size_t OFF_GATE2 = 671744;     // 524288
    constexpr size_t OFF_NORM  = 1196032;    // 8192
    constexpr size_t OFF_W     = 1204224;    // 294912 -> ends 1499136
    constexpr size_t OFF_PS    = 1499136;    // 2097152
    constexpr size_t OFF_PS2   = 3596288;    // 2097152 -> ends 5693440
    // arenas (lifetime-overlapped), as R3:
    // A (32MB): X1 -> Y1b -> QS2 -> Y2a
    // B (64MB): QS1 -> Y1a -> X2(40MB)+F1(@40MB) -> Y2b
    constexpr size_t OFF_A     = 5693440;    // 33554432
    constexpr size_t OFF_B     = 39247872;   // 67108864 -> ends 106356736
    constexpr size_t OFF_F1    = OFF_B + 41943040;

    float* q1c   = (float*)(ws + OFF_Q1C);
    float* gate1 = (float*)(ws + OFF_GATE1);
    float* q2c   = (float*)(ws + OFF_Q2C);
    float* gate2 = (float*)(ws + OFF_GATE2);
    float* n1a   = (float*)(ws + OFF_NORM);
    float* n1b   = (float*)(ws + OFF_NORM + 512);
    float* n2a   = (float*)(ws + OFF_NORM + 1536);
    float* n2b   = (float*)(ws + OFF_NORM + 2560);
    short* w1aH  = (short*)(ws + OFF_W);
    short* w1aL  = w1aH + 2048;
    short* w1bH  = w1aL + 2048;
    short* w1bL  = w1bH + 8192;
    short* w2aH  = w1bL + 8192;
    short* w2aL  = w2aH + 20480;
    short* w2bH  = w2aL + 20480;
    short* w2bL  = w2bH + 32768;
    float* pS    = (float*)(ws + OFF_PS);
    float* pS2   = (float*)(ws + OFF_PS2);

    char* A = ws + OFF_A;
    char* B = ws + OFF_B;
    short* X1  = (short*)A;
    short* Y1a = (short*)B;
    short* Y1b = (short*)A;
    short* X2  = (short*)B;
    short* Y2a = (short*)A;
    short* Y2b = (short*)B;
    float* qs1 = (float*)B;
    float* qs2 = (float*)A;
    float* f1  = (float*)(ws + OFF_F1);

    const float r2_1 = (float)(0.15 * 0.15);
    const float r2_2 = (float)(0.3 * 0.3);

    prep_w<<<8,   256, 0, stream>>>(w1a, 64, 6, 32, w1aH, w1aL);
    prep_w<<<32,  256, 0, stream>>>(w1b, 128, 64, 64, w1bH, w1bL);
    prep_w<<<80,  256, 0, stream>>>(w2a, 128, 131, 160, w2aH, w2aL);
    prep_w<<<128, 256, 0, stream>>>(w2b, 256, 128, 128, w2bH, w2bL);

    // ---------------- SA module 1 (N=512 -> 256, ns=16) ----------------
    shift_kernel<512><<<192, 256, 0, stream>>>(xyz, qs1);
    fps_kernel<512, 256><<<32, 64, 0, stream>>>(qs1, q1c);
    ballq_kernel<512, 256, 16, 3, 32><<<2048, 256, 0, stream>>>(
        xyz, q1c, xyz, r2_1, 0.15f, X1, gate1);
    mfma_conv<32, 64, false><<<CGRID, 256, 0, stream>>>(X1, w1aH, w1aL, nullptr, Y1a, pS, pS2);
    stats_fin<64><<<64, 256, 0, stream>>>(pS, pS2, g1a, b1a, n1a);
    mfma_conv<64, 128, true><<<CGRID, 256, 0, stream>>>(Y1a, w1bH, w1bL, n1a, Y1b, pS, pS2);
    stats_fin<128><<<128, 256, 0, stream>>>(pS, pS2, g1b, b1b, n1b);
    pool1_kernel<16, 256, 128><<<4096, 256, 0, stream>>>(Y1b, n1b, gate1, f1);

    // ---------------- SA module 2 (N=256 -> 128, ns=32) ----------------
    shift_kernel<256><<<96, 256, 0, stream>>>(q1c, qs2);
    fps_kernel<256, 128><<<32, 64, 0, stream>>>(qs2, q2c);
    ballq_kernel<256, 128, 32, 128, 160><<<1024, 256, 0, stream>>>(
        q1c, q2c, f1, r2_2, 0.3f, X2, gate2);
    mfma_conv<160, 128, false><<<CGRID, 256, 0, stream>>>(X2, w2aH, w2aL, nullptr, Y2a, pS, pS2);
    stats_fin<128><<<128, 256, 0, stream>>>(pS, pS2, g2a, b2a, n2a);
    mfma_conv<128, 256, true><<<CGRID, 256, 0, stream>>>(Y2a, w2bH, w2bL, n2a, Y2b, pS, pS2);
    stats_fin<256><<<256, 256, 0, stream>>>(pS, pS2, g2b, b2b, n2b);
    pool2_kernel<<<256, 256, 0, stream>>>(Y2b, n2b, gate2, (float*)d_out);
}

// Round 5
// 409.531 us; speedup vs baseline: 3.4620x; 1.1047x over previous
//
#include <hip/hip_runtime.h>
#include <hip/hip_bf16.h>
#include <math.h>

// MotionNet: PointNet++-style 2-level SA.  B=32, L=16, N=512.
// M = B*npoint*nsample = 131072 for all four conv layers.
//
// R5: FPS argmax restructured for latency — lane-major candidate order makes
// "first max" == lowest winning lane, so the 64-lane reduction is a plain
// 6-stage v_max_f32 DPP chain (single register), winner via ballot+ctz, and
// the farthest point's coords are tracked in registers and extracted with
// v_readlane (no serial LDS round-trip in the step loop).
// Convs: MFMA bf16 split-precision, LDS-staged fragment-major W, fused BN
// stats (R4).  Exactness discipline unchanged.

#define BATCH 32
#define MCOLS 131072
#define CGRID 2048            // MCOLS / 64 conv blocks

typedef __attribute__((ext_vector_type(8))) short short8;
typedef __attribute__((ext_vector_type(4))) short short4v;
typedef __attribute__((ext_vector_type(4))) float f32x4;

__device__ __forceinline__ float b2f(short s) {
    return __uint_as_float(((unsigned)(unsigned short)s) << 16);
}
__device__ __forceinline__ short f2b(float f) {
    __hip_bfloat16 h = __float2bfloat16(f);
    return (short)__builtin_bit_cast(unsigned short, h);
}
__device__ __forceinline__ float dpp_row16_sum(float v) {
    int x;
    x = __builtin_amdgcn_update_dpp(0, __float_as_int(v), 0x111, 0xf, 0xf, true);
    v += __int_as_float(x);
    x = __builtin_amdgcn_update_dpp(0, __float_as_int(v), 0x112, 0xf, 0xf, true);
    v += __int_as_float(x);
    x = __builtin_amdgcn_update_dpp(0, __float_as_int(v), 0x114, 0xf, 0xf, true);
    v += __int_as_float(x);
    x = __builtin_amdgcn_update_dpp(0, __float_as_int(v), 0x118, 0xf, 0xf, true);
    v += __int_as_float(x);
    return v;
}
template<int C>
__device__ __forceinline__ float dpp_max(float v) {
    int x = __builtin_amdgcn_update_dpp(0, __float_as_int(v), C, 0xf, 0xf, true);
    return fmaxf(v, __int_as_float(x));
}
__device__ __forceinline__ float readlane_f(float v, int lane) {
    return __int_as_float(__builtin_amdgcn_readlane(__float_as_int(v), lane));
}

// ---------------------------------------------------------------- weight prep
// w (O,C) f32 -> hi/lo packed fragment-major, zero-padded cols C..CK-1.
__global__ void prep_w(const float* __restrict__ w, int O, int C, int CK,
                       short* __restrict__ hi, short* __restrict__ lo) {
    int t = blockIdx.x * 256 + threadIdx.x;
    if (t >= O * CK) return;
    int o = t / CK, c = t % CK;
    float f = (c < C) ? w[o * C + c] : 0.f;
    short h = f2b(f);
    float fh = b2f(h);
    int NT = O >> 4;
    int ot = o >> 4, l15 = o & 15;
    int kc = c >> 5, quad = (c & 31) >> 3, j = c & 7;
    size_t idx = (((size_t)kc * NT + ot) * 64 + quad * 16 + l15) * 8 + j;
    hi[idx] = h;
    lo[idx] = f2b(f - fh);
}

// ---------------------------------------------------------------- shift
template<int N>
__global__ void shift_kernel(const float* __restrict__ xyz, float* __restrict__ qout) {
    int t = blockIdx.x * 256 + threadIdx.x;
    if (t >= BATCH * N * 3) return;
    int c = t % 3;
    int n = (t / 3) % N;
    int b = t / (3 * N);
    int l = b & 15;
    float v;
    if (l < 15) {
        v = xyz[((size_t)(b + 1) * N + n) * 3 + c];
    } else {
        int g0 = b - 15;
        float acc = 0.f;
        for (int i = 0; i < 15; ++i) {
            float d = __fsub_rn(xyz[((size_t)(g0 + i + 1) * N + n) * 3 + c],
                                xyz[((size_t)(g0 + i) * N + n) * 3 + c]);
            acc = __fadd_rn(acc, d);
        }
        v = __fadd_rn(xyz[((size_t)b * N + n) * 3 + c], __fdiv_rn(acc, 15.f));
    }
    qout[t] = v;
}

// ---------------------------------------------------------------- FPS
// One wave per batch.  Lane-major candidates (j = lane*P + p): first-max ==
// lowest winner lane, then lowest p.  Reduction: 6x v_max_f32 DPP ->
// readlane(63) -> ballot(==) -> ctz -> readlane coords.  No LDS in the loop.
template<int N, int NPOINT>
__global__ __launch_bounds__(64) void fps_kernel(const float* __restrict__ q,
                                                 float* __restrict__ qsel) {
    int b = blockIdx.x;
    int lane = threadIdx.x;
    constexpr int P = N / 64;
    __shared__ float4 qp[N];
    __shared__ int sel[NPOINT];
    const float* qb = q + (size_t)b * N * 3;
    for (int j = lane; j < N; j += 64)
        qp[j] = make_float4(qb[j * 3 + 0], qb[j * 3 + 1], qb[j * 3 + 2], 0.f);
    if (lane == 0) sel[0] = 0;
    __syncthreads();
    float px[P], py[P], pz[P], mind[P];
#pragma unroll
    for (int p = 0; p < P; ++p) {
        float4 v = qp[lane * P + p];
        px[p] = v.x; py[p] = v.y; pz[p] = v.z;
        mind[p] = 1e10f;
    }
    float4 L0 = qp[0];
    float lx = L0.x, ly = L0.y, lz = L0.z;
    for (int s = 1; s < NPOINT; ++s) {
        float bestd = -1.f;
        int bestp = 0;
        float bx = 0.f, by = 0.f, bz = 0.f;
#pragma unroll
        for (int p = 0; p < P; ++p) {
            float dx = __fsub_rn(px[p], lx);
            float dy = __fsub_rn(py[p], ly);
            float dz = __fsub_rn(pz[p], lz);
            float d = __fadd_rn(__fadd_rn(__fmul_rn(dx, dx), __fmul_rn(dy, dy)),
                                __fmul_rn(dz, dz));
            float mn = fminf(mind[p], d);
            mind[p] = mn;
            bool g = mn > bestd;               // strict: keeps smallest p
            bestd = g ? mn : bestd;
            bestp = g ? p : bestp;
            bx = g ? px[p] : bx;
            by = g ? py[p] : by;
            bz = g ? pz[p] : bz;
        }
        float m = bestd;
        m = dpp_max<0x111>(m);
        m = dpp_max<0x112>(m);
        m = dpp_max<0x114>(m);
        m = dpp_max<0x118>(m);
        m = dpp_max<0x142>(m);
        m = dpp_max<0x143>(m);
        float maxd = readlane_f(m, 63);
        unsigned long long msk = __ballot(bestd == maxd);
        int winner = (int)__builtin_ctzll(msk);
        int wp = __builtin_amdgcn_readlane(bestp, winner);
        int last = winner * P + wp;
        lx = readlane_f(bx, winner);
        ly = readlane_f(by, winner);
        lz = readlane_f(bz, winner);
        if (lane == 0) sel[s] = last;
    }
    __syncthreads();
    for (int i = lane; i < NPOINT; i += 64) {
        float4 Pt = qp[sel[i]];
        size_t o = ((size_t)b * NPOINT + i) * 3;
        qsel[o + 0] = Pt.x;
        qsel[o + 1] = Pt.y;
        qsel[o + 2] = Pt.z;
    }
}

// ---------------------------------------------------------------- ball query
template<int N, int NPOINT, int NS, int CF, int CK>
__global__ __launch_bounds__(256) void ballq_kernel(
        const float* __restrict__ xyz,    // (B,N,3)
        const float* __restrict__ qpts,   // (B,NPOINT,3)
        const float* __restrict__ feats,  // (B,N,CF)
        float r2, float radius,
        short* __restrict__ X, float* __restrict__ gate) {
    static_assert((NS & (NS - 1)) == 0, "NS pow2");
    int lane = threadIdx.x & 63;
    int wib = threadIdx.x >> 6;
    int wid = blockIdx.x * 4 + wib;
    int b = wid / NPOINT;
    int i = wid % NPOINT;
    const float* qp = qpts + ((size_t)b * NPOINT + i) * 3;
    float qx = qp[0], qy = qp[1], qz = qp[2];
    __shared__ int gsh[4][NS];
    int* gidx = gsh[wib];
    int taken = 0, first = 0;
    bool any = false;
#pragma unroll
    for (int base = 0; base < N; base += 64) {
        int j = base + lane;
        const float* p = xyz + ((size_t)b * N + j) * 3;
        float dx = __fsub_rn(qx, p[0]);
        float dy = __fsub_rn(qy, p[1]);
        float dz = __fsub_rn(qz, p[2]);
        float d2 = __fadd_rn(__fadd_rn(__fmul_rn(dx, dx), __fmul_rn(dy, dy)),
                             __fmul_rn(dz, dz));
        bool in = d2 < r2;
        unsigned long long mk = __ballot(in);
        if (!any && mk) { first = base + __builtin_ctzll(mk); any = true; }
        int cb = __builtin_popcountll(mk & ((1ull << lane) - 1ull));
        int slot = taken + cb;
        if (in && slot < NS) gidx[slot] = j;
        taken += (int)__builtin_popcountll(mk);
    }
    if (taken < NS) {
        for (int s = taken + lane; s < NS; s += 64) gidx[s] = any ? first : 0;
    }
    __syncthreads();
    int m0 = (b * NPOINT + i) * NS;
    if (lane < NS) {
        int g = gidx[lane];
        const float* p = xyz + ((size_t)b * N + g) * 3;
        float dx = (p[0] - qx) / radius;
        float dy = (p[1] - qy) / radius;
        float dz = (p[2] - qz) / radius;
        float dist = sqrtf(dx * dx + dy * dy + dz * dz);
        gate[m0 + lane] = 1.f / (1.f + expf(-dist));
    }
    for (int e = lane; e < NS * CK; e += 64) {
        int s = e / CK;
        int c = e % CK;
        int g = gidx[s];
        float v;
        if (c < 3) {
            float qc = (c == 0) ? qx : ((c == 1) ? qy : qz);
            v = (xyz[((size_t)b * N + g) * 3 + c] - qc) / radius;
        } else if (c < 3 + CF) {
            v = feats[((size_t)b * N + g) * CF + (c - 3)];
        } else {
            v = 0.f;
        }
        X[(size_t)(m0 + s) * CK + c] = f2b(v);
    }
}

// ---------------------------------------------------------------- MFMA conv
// X (M,CK) bf16 -> Y (M,O) bf16.  W chunks staged in LDS per k-step
// (fragment-major, coalesced, shared by all 4 waves).  Waves split O.
// Fused BN stats: f32 acc sums -> DPP row16 reduce -> per-block partials.
template<int CK, int O, bool AFF>
__global__ __launch_bounds__(256, 3) void mfma_conv(
        const short* __restrict__ X, const short* __restrict__ Whi,
        const short* __restrict__ Wlo, const float* __restrict__ ss,
        short* __restrict__ Y, float* __restrict__ pS, float* __restrict__ pS2) {
    constexpr int KC = CK / 32;
    constexpr int NT = O / 16;
    constexpr int OW = NT / 4;
    constexpr int LR = CK + 8;
    constexpr int CB = CK / 8;
    __shared__ __align__(16) short xs[64 * LR];
    __shared__ __align__(16) short wh[NT * 512];
    __shared__ __align__(16) short wl[NT * 512];
    __shared__ float ssl[AFF ? 2 * CK : 1];
    __shared__ float sblk[O], s2blk[O];
    int tid = threadIdx.x;
    int m0 = blockIdx.x * 64;

    if constexpr (AFF) {
        for (int i = tid; i < 2 * CK; i += 256) ssl[i] = ss[i];
        __syncthreads();
    }
    for (int idx = tid; idx < 64 * CB; idx += 256) {
        int r = idx / CB;
        int col = (idx % CB) * 8;
        short8 v = *(const short8*)(X + (size_t)(m0 + r) * CK + col);
        if constexpr (AFF) {
#pragma unroll
            for (int i = 0; i < 8; ++i) {
                float f = b2f(v[i]);
                f = fmaf(f, ssl[col + i], ssl[CK + col + i]);
                f = f > 0.f ? f : 0.2f * f;
                v[i] = f2b(f);
            }
        }
        *(short8*)(xs + r * LR + col) = v;
    }

    int lane = tid & 63;
    int wave = tid >> 6;
    int l15 = lane & 15;
    int quad = lane >> 4;
    int obase = wave * OW * 16;

    f32x4 acc[4][OW];
#pragma unroll
    for (int mt = 0; mt < 4; ++mt)
#pragma unroll
        for (int ot = 0; ot < OW; ++ot) acc[mt][ot] = (f32x4){0.f, 0.f, 0.f, 0.f};

    for (int kc = 0; kc < KC; ++kc) {
        __syncthreads();
        {
            const short8* gH = (const short8*)Whi + (size_t)kc * NT * 64;
            const short8* gL = (const short8*)Wlo + (size_t)kc * NT * 64;
            short8* lH = (short8*)wh;
            short8* lL = (short8*)wl;
            for (int i = tid; i < NT * 64; i += 256) { lH[i] = gH[i]; lL[i] = gL[i]; }
        }
        __syncthreads();
        short8 bf[4];
#pragma unroll
        for (int mt = 0; mt < 4; ++mt)
            bf[mt] = *(const short8*)(xs + (mt * 16 + l15) * LR + kc * 32 + quad * 8);
#pragma unroll
        for (int ot = 0; ot < OW; ++ot) {
            short8 ah = ((const short8*)wh)[(wave * OW + ot) * 64 + lane];
            short8 al = ((const short8*)wl)[(wave * OW + ot) * 64 + lane];
#pragma unroll
            for (int mt = 0; mt < 4; ++mt) {
                acc[mt][ot] = __builtin_amdgcn_mfma_f32_16x16x32_bf16(ah, bf[mt], acc[mt][ot], 0, 0, 0);
                acc[mt][ot] = __builtin_amdgcn_mfma_f32_16x16x32_bf16(al, bf[mt], acc[mt][ot], 0, 0, 0);
            }
        }
    }

#pragma unroll
    for (int mt = 0; mt < 4; ++mt) {
        size_t ybase = (size_t)(m0 + mt * 16 + l15) * O + obase + quad * 4;
#pragma unroll
        for (int ot = 0; ot < OW; ++ot) {
            short4v pk;
#pragma unroll
            for (int r4 = 0; r4 < 4; ++r4) pk[r4] = f2b(acc[mt][ot][r4]);
            *(short4v*)(Y + ybase + ot * 16) = pk;
        }
    }
#pragma unroll
    for (int ot = 0; ot < OW; ++ot) {
#pragma unroll
        for (int r4 = 0; r4 < 4; ++r4) {
            float s = 0.f, s2 = 0.f;
#pragma unroll
            for (int mt = 0; mt < 4; ++mt) {
                float v = acc[mt][ot][r4];
                s += v;
                s2 = fmaf(v, v, s2);
            }
            s = dpp_row16_sum(s);
            s2 = dpp_row16_sum(s2);
            if (l15 == 15) {
                int o = obase + ot * 16 + quad * 4 + r4;
                sblk[o] = s;
                s2blk[o] = s2;
            }
        }
    }
    __syncthreads();
    for (int o = tid; o < O; o += 256) {
        pS [(size_t)o * CGRID + blockIdx.x] = sblk[o];
        pS2[(size_t)o * CGRID + blockIdx.x] = s2blk[o];
    }
}

// ---------------------------------------------------------------- BN finalize
template<int O>
__global__ __launch_bounds__(256) void stats_fin(
        const float* __restrict__ pS, const float* __restrict__ pS2,
        const float* __restrict__ gm, const float* __restrict__ bt,
        float* __restrict__ norm) {
    int o = blockIdx.x;
    float s = 0.f, s2 = 0.f;
    for (int p = threadIdx.x; p < CGRID; p += 256) {
        s += pS[(size_t)o * CGRID + p];
        s2 += pS2[(size_t)o * CGRID + p];
    }
#pragma unroll
    for (int off = 32; off >= 1; off >>= 1) {
        s  += __shfl_xor(s,  off, 64);
        s2 += __shfl_xor(s2, off, 64);
    }
    __shared__ float sh[8];
    int wid = threadIdx.x >> 6;
    if ((threadIdx.x & 63) == 0) { sh[wid] = s; sh[4 + wid] = s2; }
    __syncthreads();
    if (threadIdx.x == 0) {
        float S  = sh[0] + sh[1] + sh[2] + sh[3];
        float S2 = sh[4] + sh[5] + sh[6] + sh[7];
        const float invM = 1.f / (float)MCOLS;
        float mu = S * invM;
        float var = S2 * invM - mu * mu;
        float sc = gm[o] * rsqrtf(var + 1e-5f);
        norm[o] = sc;
        norm[O + o] = bt[o] - mu * sc;
    }
}

// ---------------------------------------------------------------- pool 1
template<int NS, int NPOINT, int O>
__global__ __launch_bounds__(256) void pool1_kernel(
        const short* __restrict__ Y, const float* __restrict__ norm,
        const float* __restrict__ gate, float* __restrict__ out) {
    int t = blockIdx.x * 256 + threadIdx.x;
    int o = t % O;
    int n = (t / O) % NPOINT;
    int b = t / (O * NPOINT);
    int m0 = (b * NPOINT + n) * NS;
    float sc = norm[o], sf = norm[O + o];
    float best = -INFINITY;
#pragma unroll
    for (int k = 0; k < NS; ++k) {
        float v = fmaf(b2f(Y[(size_t)(m0 + k) * O + o]), sc, sf);
        v = v > 0.f ? v : 0.2f * v;
        best = fmaxf(best, gate[m0 + k] * v);
    }
    out[t] = best;
}

// ---------------------------------------------------------------- pool 2
__global__ __launch_bounds__(256) void pool2_kernel(
        const short* __restrict__ Y, const float* __restrict__ norm,
        const float* __restrict__ gate, float* __restrict__ out) {
    constexpr int NS = 32, NPOINT = 128, O = 256;
    int b  = blockIdx.x >> 3;
    int oc = (blockIdx.x >> 1) & 3;
    int nc = blockIdx.x & 1;
    __shared__ float trans[64][65];
    int tid = threadIdx.x;
    for (int w = 0; w < 16; ++w) {
        int idx = w * 256 + tid;
        int o_l = idx & 63;
        int n_l = idx >> 6;
        int o = oc * 64 + o_l;
        int n = nc * 64 + n_l;
        int m0 = (b * NPOINT + n) * NS;
        float sc = norm[o], sf = norm[O + o];
        float best = -INFINITY;
#pragma unroll
        for (int k = 0; k < NS; ++k) {
            float v = fmaf(b2f(Y[(size_t)(m0 + k) * O + o]), sc, sf);
            v = v > 0.f ? v : 0.2f * v;
            best = fmaxf(best, gate[m0 + k] * v);
        }
        trans[o_l][n_l] = best;
    }
    __syncthreads();
    for (int w = 0; w < 16; ++w) {
        int idx = w * 256 + tid;
        int o_l = idx >> 6;
        int n_l = idx & 63;
        out[((size_t)b * O + oc * 64 + o_l) * NPOINT + nc * 64 + n_l] = trans[o_l][n_l];
    }
}

// ---------------------------------------------------------------- launch
extern "C" void kernel_launch(void* const* d_in, const int* in_sizes, int n_in,
                              void* d_out, int out_size, void* d_ws, size_t ws_size,
                              hipStream_t stream) {
    const float* xyz = (const float*)d_in[0];
    const float* w1a = (const float*)d_in[1];
    const float* g1a = (const float*)d_in[2];
    const float* b1a = (const float*)d_in[3];
    const float* w1b = (const float*)d_in[4];
    const float* g1b = (const float*)d_in[5];
    const float* b1b = (const float*)d_in[6];
    const float* w2a = (const float*)d_in[7];
    const float* g2a = (const float*)d_in[8];
    const float* b2a = (const float*)d_in[9];
    const float* w2b = (const float*)d_in[10];
    const float* g2b = (const float*)d_in[11];
    const float* b2b = (const float*)d_in[12];

    char* ws = (char*)d_ws;
    constexpr size_t OFF_Q1C   = 0;          // 98304
    constexpr size_t OFF_GATE1 = 98304;      // 524288
    constexpr size_t OFF_Q2C   = 622592;     // 49152
    constexpr size_t OFF_GATE2 = 671744;     // 524288
    constexpr size_t OFF_NORM  = 1196032;    // 8192
    constexpr size_t OFF_W     = 1204224;    // 294912 -> ends 1499136
    constexpr size_t OFF_PS    = 1499136;    // 2097152
    constexpr size_t OFF_PS2   = 3596288;    // 2097152 -> ends 5693440
    constexpr size_t OFF_A     = 5693440;    // 33554432
    constexpr size_t OFF_B     = 39247872;   // 67108864 -> ends 106356736
    constexpr size_t OFF_F1    = OFF_B + 41943040;

    float* q1c   = (float*)(ws + OFF_Q1C);
    float* gate1 = (float*)(ws + OFF_GATE1);
    float* q2c   = (float*)(ws + OFF_Q2C);
    float* gate2 = (float*)(ws + OFF_GATE2);
    float* n1a   = (float*)(ws + OFF_NORM);
    float* n1b   = (float*)(ws + OFF_NORM + 512);
    float* n2a   = (float*)(ws + OFF_NORM + 1536);
    float* n2b   = (float*)(ws + OFF_NORM + 2560);
    short* w1aH  = (short*)(ws + OFF_W);
    short* w1aL  = w1aH + 2048;
    short* w1bH  = w1aL + 2048;
    short* w1bL  = w1bH + 8192;
    short* w2aH  = w1bL + 8192;
    short* w2aL  = w2aH + 20480;
    short* w2bH  = w2aL + 20480;
    short* w2bL  = w2bH + 32768;
    float* pS    = (float*)(ws + OFF_PS);
    float* pS2   = (float*)(ws + OFF_PS2);

    char* A = ws + OFF_A;
    char* B = ws + OFF_B;
    short* X1  = (short*)A;
    short* Y1a = (short*)B;
    short* Y1b = (short*)A;
    short* X2  = (short*)B;
    short* Y2a = (short*)A;
    short* Y2b = (short*)B;
    float* qs1 = (float*)B;
    float* qs2 = (float*)A;
    float* f1  = (float*)(ws + OFF_F1);

    const float r2_1 = (float)(0.15 * 0.15);
    const float r2_2 = (float)(0.3 * 0.3);

    prep_w<<<8,   256, 0, stream>>>(w1a, 64, 6, 32, w1aH, w1aL);
    prep_w<<<32,  256, 0, stream>>>(w1b, 128, 64, 64, w1bH, w1bL);
    prep_w<<<80,  256, 0, stream>>>(w2a, 128, 131, 160, w2aH, w2aL);
    prep_w<<<128, 256, 0, stream>>>(w2b, 256, 128, 128, w2bH, w2bL);

    // ---------------- SA module 1 (N=512 -> 256, ns=16) ----------------
    shift_kernel<512><<<192, 256, 0, stream>>>(xyz, qs1);
    fps_kernel<512, 256><<<32, 64, 0, stream>>>(qs1, q1c);
    ballq_kernel<512, 256, 16, 3, 32><<<2048, 256, 0, stream>>>(
        xyz, q1c, xyz, r2_1, 0.15f, X1, gate1);
    mfma_conv<32, 64, false><<<CGRID, 256, 0, stream>>>(X1, w1aH, w1aL, nullptr, Y1a, pS, pS2);
    stats_fin<64><<<64, 256, 0, stream>>>(pS, pS2, g1a, b1a, n1a);
    mfma_conv<64, 128, true><<<CGRID, 256, 0, stream>>>(Y1a, w1bH, w1bL, n1a, Y1b, pS, pS2);
    stats_fin<128><<<128, 256, 0, stream>>>(pS, pS2, g1b, b1b, n1b);
    pool1_kernel<16, 256, 128><<<4096, 256, 0, stream>>>(Y1b, n1b, gate1, f1);

    // ---------------- SA module 2 (N=256 -> 128, ns=32) ----------------
    shift_kernel<256><<<96, 256, 0, stream>>>(q1c, qs2);
    fps_kernel<256, 128><<<32, 64, 0, stream>>>(qs2, q2c);
    ballq_kernel<256, 128, 32, 128, 160><<<1024, 256, 0, stream>>>(
        q1c, q2c, f1, r2_2, 0.3f, X2, gate2);
    mfma_conv<160, 128, false><<<CGRID, 256, 0, stream>>>(X2, w2aH, w2aL, nullptr, Y2a, pS, pS2);
    stats_fin<128><<<128, 256, 0, stream>>>(pS, pS2, g2a, b2a, n2a);
    mfma_conv<128, 256, true><<<CGRID, 256, 0, stream>>>(Y2a, w2bH, w2bL, n2a, Y2b, pS, pS2);
    stats_fin<256><<<256, 256, 0, stream>>>(pS, pS2, g2b, b2b, n2b);
    pool2_kernel<<<256, 256, 0, stream>>>(Y2b, n2b, gate2, (float*)d_out);
}